// Round 1
// baseline (3103.279 us; speedup 1.0000x reference)
//
#include <hip/hip_runtime.h>

typedef unsigned short u16;
typedef unsigned int u32;
typedef __bf16 bf16x8 __attribute__((ext_vector_type(8)));
typedef u16 u16x8 __attribute__((ext_vector_type(8)));
typedef float f32x4 __attribute__((ext_vector_type(4)));

__device__ __forceinline__ u16 f2bf(float f) {
  u32 u = __float_as_uint(f);
  u32 r = (u + 0x7FFFu + ((u >> 16) & 1u)) >> 16;  // RNE
  return (u16)r;
}

// ---------------- kernel 0: cast x fp32 -> bf16 A[4608][512] ----------------
__global__ void k_cast(const float* __restrict__ x, u16* __restrict__ A) {
  int t = blockIdx.x * 256 + threadIdx.x;  // 294912 threads, 8 elems each
  const float4* xp = (const float4*)x + (size_t)t * 2;
  float4 v0 = xp[0], v1 = xp[1];
  u16x8 r;
  r[0] = f2bf(v0.x); r[1] = f2bf(v0.y); r[2] = f2bf(v0.z); r[3] = f2bf(v0.w);
  r[4] = f2bf(v1.x); r[5] = f2bf(v1.y); r[6] = f2bf(v1.z); r[7] = f2bf(v1.w);
  *(u16x8*)(A + (size_t)t * 8) = r;
}

// ------- kernel 1: C = A*A^T with fused max over p (col groups of 9) -------
// Tile: 64 rows x 144 cols (144 = LCM(16,9)); writes Smax[4608][512]
__global__ __launch_bounds__(256) void k_gemm_smax(const u16* __restrict__ A,
                                                   float* __restrict__ Smax) {
  __shared__ float smemf[64 * 148];  // 37888 B; overlaid: staging then C-tile
  u16* As = (u16*)smemf;             // 64 rows x 40 (pad; 80 B stride, 16B-aligned)
  u16* Bs = As + 64 * 40;            // 144 rows x 40
  const int rb = blockIdx.x, cb = blockIdx.y;
  const int rowBase = rb * 64, colBase = cb * 144;
  const int tid = threadIdx.x;
  const int wave = tid >> 6, lane = tid & 63;
  const int lrow = lane & 15, lk = lane >> 4;

  f32x4 acc[9];
#pragma unroll
  for (int t = 0; t < 9; ++t) { f32x4 z = {0.f, 0.f, 0.f, 0.f}; acc[t] = z; }

  for (int k0 = 0; k0 < 512; k0 += 32) {
    __syncthreads();
    {
      int row = tid >> 2, kc = tid & 3;  // 256 chunks exactly for As
      *(float4*)(As + row * 40 + kc * 8) =
          *(const float4*)(A + (size_t)(rowBase + row) * 512 + k0 + kc * 8);
      for (int c = tid; c < 576; c += 256) {
        int r2 = c >> 2, k2 = c & 3;
        *(float4*)(Bs + r2 * 40 + k2 * 8) =
            *(const float4*)(A + (size_t)(colBase + r2) * 512 + k0 + k2 * 8);
      }
    }
    __syncthreads();
    bf16x8 af = *(const bf16x8*)(As + (wave * 16 + lrow) * 40 + lk * 8);
#pragma unroll
    for (int t = 0; t < 9; ++t) {
      bf16x8 bfr = *(const bf16x8*)(Bs + (t * 16 + lrow) * 40 + lk * 8);
      acc[t] = __builtin_amdgcn_mfma_f32_16x16x32_bf16(af, bfr, acc[t], 0, 0, 0);
    }
  }
  __syncthreads();
  // dump accumulators: C/D layout col=lane&15, row=(lane>>4)*4+reg [measured]
#pragma unroll
  for (int t = 0; t < 9; ++t)
#pragma unroll
    for (int r = 0; r < 4; ++r)
      smemf[(wave * 16 + lk * 4 + r) * 148 + t * 16 + lrow] = acc[t][r];
  __syncthreads();
  for (int v = tid; v < 1024; v += 256) {
    int row = v >> 4, j = v & 15;
    const float* p = smemf + row * 148 + j * 9;
    float m = p[0];
#pragma unroll
    for (int q = 1; q < 9; ++q) m = fmaxf(m, p[q]);
    Smax[(size_t)(rowBase + row) * 512 + cb * 16 + j] = m;
  }
}

// ---------- kernel 2: mean over o (row groups of 9) -> sim[64][64][64] ------
__global__ void k_reduce_o(const float* __restrict__ Smax, float* __restrict__ sim) {
  int idx = blockIdx.x * 256 + threadIdx.x;  // 262144
  int j = idx & 63, i = (idx >> 6) & 63, b = (idx >> 12) & 7, a = idx >> 15;
  const float* p = Smax + (size_t)((a * 64 + i) * 9) * 512 + b * 64 + j;
  float s = p[0];
#pragma unroll
  for (int o = 1; o < 9; ++o) s += p[o * 512];
  sim[idx] = s * (1.f / 9.f);  // sim[(a*8+b)*4096 + i*64 + j]
}

// ---------- kernel 3: conv1 (1->32, 3x3 same) + ReLU + maxpool2 -------------
__global__ __launch_bounds__(256) void k_conv1pool(const float* __restrict__ sim,
                                                   const float* __restrict__ w1,
                                                   const float* __restrict__ b1,
                                                   float* __restrict__ out) {
  __shared__ float tin[4096];  // 64x64 input
  const int pair = blockIdx.x, ocg = blockIdx.y, tid = threadIdx.x;
  const float4* src = (const float4*)(sim + (size_t)pair * 4096);
  for (int i = tid; i < 1024; i += 256) ((float4*)tin)[i] = src[i];
  __syncthreads();
  for (int oc8 = 0; oc8 < 8; ++oc8) {
    int oc = ocg * 8 + oc8;
    float wv[9];
#pragma unroll
    for (int q = 0; q < 9; ++q) wv[q] = w1[oc * 9 + q];
    float bias = b1[oc];
    for (int pp = tid; pp < 1024; pp += 256) {
      int py = pp >> 5, px = pp & 31;
      float m = 0.f;  // relu >= 0, so 0 is a valid max identity
#pragma unroll
      for (int dy = 0; dy < 2; ++dy)
#pragma unroll
        for (int dx = 0; dx < 2; ++dx) {
          int yy = py * 2 + dy, xx0 = px * 2 + dx;
          float s = bias;
#pragma unroll
          for (int ky = 0; ky < 3; ++ky) {
            int y = yy + ky - 1;
            if ((unsigned)y < 64u) {
#pragma unroll
              for (int kx = 0; kx < 3; ++kx) {
                int x = xx0 + kx - 1;
                if ((unsigned)x < 64u) s += wv[ky * 3 + kx] * tin[y * 64 + x];
              }
            }
          }
          m = fmaxf(m, fmaxf(s, 0.f));
        }
      out[(((size_t)pair * 32 + oc) * 32 + py) * 32 + px] = m;
    }
  }
}

// ---------- kernel 4: conv2 (32->64, 3x3 same) + ReLU + maxpool2 ------------
__global__ __launch_bounds__(256) void k_conv2pool(const float* __restrict__ in,
                                                   const float* __restrict__ w2,
                                                   const float* __restrict__ b2,
                                                   float* __restrict__ out) {
  __shared__ float tin[8 * 1024];  // 8-ic chunk of 32x32 images, 32 KB
  __shared__ float tw[8 * 72];     // [oc8][ic8*9]
  const int pair = blockIdx.x, ocg = blockIdx.y, tid = threadIdx.x;
  const int py = tid >> 4, px = tid & 15;
  float acc[8][4];
#pragma unroll
  for (int o = 0; o < 8; ++o)
#pragma unroll
    for (int d = 0; d < 4; ++d) acc[o][d] = 0.f;

  for (int icc = 0; icc < 4; ++icc) {
    __syncthreads();
    const float4* src = (const float4*)(in + ((size_t)pair * 32 + icc * 8) * 1024);
    for (int i = tid; i < 2048; i += 256) ((float4*)tin)[i] = src[i];
    for (int i = tid; i < 576; i += 256) {
      int oc = i / 72, r = i % 72;
      tw[i] = w2[(ocg * 8 + oc) * 288 + icc * 72 + r];
    }
    __syncthreads();
#pragma unroll
    for (int ic = 0; ic < 8; ++ic) {
      const float* ch = tin + ic * 1024;
      float win[16];  // 4x4 window covering the 2x2 pre-pool conv outputs
#pragma unroll
      for (int wy = 0; wy < 4; ++wy) {
        int y = 2 * py - 1 + wy;
#pragma unroll
        for (int wx = 0; wx < 4; ++wx) {
          int x = 2 * px - 1 + wx;
          win[wy * 4 + wx] = ((unsigned)y < 32u && (unsigned)x < 32u) ? ch[y * 32 + x] : 0.f;
        }
      }
#pragma unroll
      for (int oc = 0; oc < 8; ++oc) {
        const float* w = tw + oc * 72 + ic * 9;
#pragma unroll
        for (int d = 0; d < 4; ++d) {
          int dy = d >> 1, dx = d & 1;
          float s = acc[oc][d];
#pragma unroll
          for (int ky = 0; ky < 3; ++ky)
#pragma unroll
            for (int kx = 0; kx < 3; ++kx)
              s += w[ky * 3 + kx] * win[(dy + ky) * 4 + (dx + kx)];
          acc[oc][d] = s;
        }
      }
    }
  }
#pragma unroll
  for (int oc = 0; oc < 8; ++oc) {
    float bias = b2[ocg * 8 + oc];
    float m = 0.f;
#pragma unroll
    for (int d = 0; d < 4; ++d) m = fmaxf(m, fmaxf(acc[oc][d] + bias, 0.f));
    out[(((size_t)pair * 64 + ocg * 8 + oc) * 16 + py) * 16 + px] = m;
  }
}

// ---------- kernel 5: conv3 (64->128, 3x3 same) + ReLU ----------------------
__global__ __launch_bounds__(256) void k_conv3(const float* __restrict__ in,
                                               const float* __restrict__ w3,
                                               const float* __restrict__ b3,
                                               float* __restrict__ out) {
  __shared__ float tin[16 * 256];  // 16-ic chunk of 16x16 images
  __shared__ float tw[16 * 144];   // [oc16][ic16*9]
  const int pair = blockIdx.x, ocg = blockIdx.y, tid = threadIdx.x;
  const int y = tid >> 4, x = tid & 15;
  float acc[16];
#pragma unroll
  for (int o = 0; o < 16; ++o) acc[o] = 0.f;
  for (int icc = 0; icc < 4; ++icc) {
    __syncthreads();
    const float4* src = (const float4*)(in + ((size_t)pair * 64 + icc * 16) * 256);
    for (int i = tid; i < 1024; i += 256) ((float4*)tin)[i] = src[i];
    for (int i = tid; i < 2304; i += 256) {
      int oc = i / 144, r = i % 144;
      tw[i] = w3[(ocg * 16 + oc) * 576 + icc * 144 + r];
    }
    __syncthreads();
#pragma unroll
    for (int ic = 0; ic < 16; ++ic) {
      const float* ch = tin + ic * 256;
      float win[9];
#pragma unroll
      for (int ky = 0; ky < 3; ++ky) {
        int yy = y + ky - 1;
#pragma unroll
        for (int kx = 0; kx < 3; ++kx) {
          int xw = x + kx - 1;
          win[ky * 3 + kx] = ((unsigned)yy < 16u && (unsigned)xw < 16u) ? ch[yy * 16 + xw] : 0.f;
        }
      }
#pragma unroll
      for (int oc = 0; oc < 16; ++oc) {
        const float* w = tw + oc * 144 + ic * 9;
        float s = acc[oc];
#pragma unroll
        for (int q = 0; q < 9; ++q) s += w[q] * win[q];
        acc[oc] = s;
      }
    }
  }
#pragma unroll
  for (int oc = 0; oc < 16; ++oc)
    out[((size_t)pair * 128 + ocg * 16 + oc) * 256 + tid] =
        fmaxf(acc[oc] + b3[ocg * 16 + oc], 0.f);
}

// ---------- kernel 6: zero the output (loss accumulator) --------------------
__global__ void k_zero(float* __restrict__ out) {
  if (threadIdx.x < 65) out[threadIdx.x] = 0.f;
}

// ---------- kernel 7: conv4 1x1 (128->1) + loss + hardtanh + chamfer --------
__global__ __launch_bounds__(256) void k_conv4(const float* __restrict__ h3,
                                               const float* __restrict__ w4,
                                               const float* __restrict__ b4,
                                               float* __restrict__ out) {
  __shared__ float ws4[128];
  __shared__ float rowmax[16];
  __shared__ float lsum[4];
  const int pair = blockIdx.x, tid = threadIdx.x;
  if (tid < 128) ws4[tid] = w4[tid];
  __syncthreads();
  float h = b4[0];
  const float* p = h3 + (size_t)pair * 128 * 256 + tid;
#pragma unroll 8
  for (int ic = 0; ic < 128; ++ic) h += ws4[ic] * p[ic * 256];
  float loss = fmaxf(-(h + 1.f), 0.f) + fmaxf(h - 1.f, 0.f);
  float sc = fminf(fmaxf(h, -1.f), 1.f) * 0.5f + 0.5f;
  // max over j (x) within each row of 16 lanes
#pragma unroll
  for (int off = 8; off >= 1; off >>= 1) sc = fmaxf(sc, __shfl_xor(sc, off, 16));
  // loss: full-wave sum
#pragma unroll
  for (int off = 32; off >= 1; off >>= 1) loss += __shfl_xor(loss, off, 64);
  if ((tid & 15) == 0) rowmax[tid >> 4] = sc;
  if ((tid & 63) == 0) lsum[tid >> 6] = loss;
  __syncthreads();
  if (tid == 0) {
    float mean = 0.f;
#pragma unroll
    for (int i = 0; i < 16; ++i) mean += rowmax[i];
    out[pair] = mean * (1.f / 16.f);
    atomicAdd(out + 64, lsum[0] + lsum[1] + lsum[2] + lsum[3]);
  }
}

extern "C" void kernel_launch(void* const* d_in, const int* in_sizes, int n_in,
                              void* d_out, int out_size, void* d_ws, size_t ws_size,
                              hipStream_t stream) {
  (void)in_sizes; (void)n_in; (void)out_size; (void)ws_size;
  const float* x  = (const float*)d_in[0];
  const float* w1 = (const float*)d_in[1];
  const float* b1 = (const float*)d_in[2];
  const float* w2 = (const float*)d_in[3];
  const float* b2 = (const float*)d_in[4];
  const float* w3 = (const float*)d_in[5];
  const float* b3 = (const float*)d_in[6];
  const float* w4 = (const float*)d_in[7];
  const float* b4 = (const float*)d_in[8];
  float* out = (float*)d_out;

  char* ws = (char*)d_ws;
  u16*   Abf  = (u16*)ws;                          // 4,718,592 B
  float* Smax = (float*)(ws + 4718592);            // 9,437,184 B
  float* sim  = (float*)(ws + 14155776);           // 1,048,576 B
  float* h1   = (float*)(ws + 15204352);           // 8,388,608 B
  float* h2   = (float*)(ws + 23592960);           // 4,194,304 B
  float* h3   = (float*)(ws + 27787264);           // 8,388,608 B  (total ~34.5 MB)

  k_cast<<<1152, 256, 0, stream>>>(x, Abf);
  k_gemm_smax<<<dim3(72, 32), 256, 0, stream>>>(Abf, Smax);
  k_reduce_o<<<1024, 256, 0, stream>>>(Smax, sim);
  k_conv1pool<<<dim3(64, 4), 256, 0, stream>>>(sim, w1, b1, h1);
  k_conv2pool<<<dim3(64, 8), 256, 0, stream>>>(h1, w2, b2, h2);
  k_conv3<<<dim3(64, 8), 256, 0, stream>>>(h2, w3, b3, h3);
  k_zero<<<1, 128, 0, stream>>>(out);
  k_conv4<<<64, 256, 0, stream>>>(h3, w4, b4, out);
}

// Round 2
// 485.374 us; speedup vs baseline: 6.3936x; 6.3936x over previous
//
#include <hip/hip_runtime.h>

typedef unsigned short u16;
typedef unsigned int u32;
typedef __bf16 bf16x8 __attribute__((ext_vector_type(8)));
typedef u16 u16x8 __attribute__((ext_vector_type(8)));
typedef float f32x4 __attribute__((ext_vector_type(4)));

__device__ __forceinline__ u16 f2bf(float f) {
  u32 u = __float_as_uint(f);
  u32 r = (u + 0x7FFFu + ((u >> 16) & 1u)) >> 16;  // RNE
  return (u16)r;
}

// ---------------- kernel 0: cast x fp32 -> bf16 A[4608][512] ----------------
__global__ void k_cast(const float* __restrict__ x, u16* __restrict__ A) {
  int t = blockIdx.x * 256 + threadIdx.x;  // 294912 threads, 8 elems each
  const float4* xp = (const float4*)x + (size_t)t * 2;
  float4 v0 = xp[0], v1 = xp[1];
  u16x8 r;
  r[0] = f2bf(v0.x); r[1] = f2bf(v0.y); r[2] = f2bf(v0.z); r[3] = f2bf(v0.w);
  r[4] = f2bf(v1.x); r[5] = f2bf(v1.y); r[6] = f2bf(v1.z); r[7] = f2bf(v1.w);
  *(u16x8*)(A + (size_t)t * 8) = r;
}

// ------- kernel 1: C = A*A^T with fused max over p (col groups of 9) -------
// Tile: 64 rows x 144 cols (144 = LCM(16,9)); writes Smax[4608][512]
__global__ __launch_bounds__(256) void k_gemm_smax(const u16* __restrict__ A,
                                                   float* __restrict__ Smax) {
  __shared__ float smemf[64 * 148];  // 37888 B; overlaid: staging then C-tile
  u16* As = (u16*)smemf;             // 64 rows x 40 (pad; 80 B stride, 16B-aligned)
  u16* Bs = As + 64 * 40;            // 144 rows x 40
  const int rb = blockIdx.x, cb = blockIdx.y;
  const int rowBase = rb * 64, colBase = cb * 144;
  const int tid = threadIdx.x;
  const int wave = tid >> 6, lane = tid & 63;
  const int lrow = lane & 15, lk = lane >> 4;

  f32x4 acc[9];
#pragma unroll
  for (int t = 0; t < 9; ++t) { f32x4 z = {0.f, 0.f, 0.f, 0.f}; acc[t] = z; }

  for (int k0 = 0; k0 < 512; k0 += 32) {
    __syncthreads();
    {
      int row = tid >> 2, kc = tid & 3;  // 256 chunks exactly for As
      *(float4*)(As + row * 40 + kc * 8) =
          *(const float4*)(A + (size_t)(rowBase + row) * 512 + k0 + kc * 8);
      for (int c = tid; c < 576; c += 256) {
        int r2 = c >> 2, k2 = c & 3;
        *(float4*)(Bs + r2 * 40 + k2 * 8) =
            *(const float4*)(A + (size_t)(colBase + r2) * 512 + k0 + k2 * 8);
      }
    }
    __syncthreads();
    bf16x8 af = *(const bf16x8*)(As + (wave * 16 + lrow) * 40 + lk * 8);
#pragma unroll
    for (int t = 0; t < 9; ++t) {
      bf16x8 bfr = *(const bf16x8*)(Bs + (t * 16 + lrow) * 40 + lk * 8);
      acc[t] = __builtin_amdgcn_mfma_f32_16x16x32_bf16(af, bfr, acc[t], 0, 0, 0);
    }
  }
  __syncthreads();
  // dump accumulators: C/D layout col=lane&15, row=(lane>>4)*4+reg [measured]
#pragma unroll
  for (int t = 0; t < 9; ++t)
#pragma unroll
    for (int r = 0; r < 4; ++r)
      smemf[(wave * 16 + lk * 4 + r) * 148 + t * 16 + lrow] = acc[t][r];
  __syncthreads();
  for (int v = tid; v < 1024; v += 256) {
    int row = v >> 4, j = v & 15;
    const float* p = smemf + row * 148 + j * 9;
    float m = p[0];
#pragma unroll
    for (int q = 1; q < 9; ++q) m = fmaxf(m, p[q]);
    Smax[(size_t)(rowBase + row) * 512 + cb * 16 + j] = m;
  }
}

// ---------- kernel 2: mean over o (row groups of 9) -> sim[64][64][64] ------
__global__ void k_reduce_o(const float* __restrict__ Smax, float* __restrict__ sim) {
  int idx = blockIdx.x * 256 + threadIdx.x;  // 262144
  int j = idx & 63, i = (idx >> 6) & 63, b = (idx >> 12) & 7, a = idx >> 15;
  const float* p = Smax + (size_t)((a * 64 + i) * 9) * 512 + b * 64 + j;
  float s = p[0];
#pragma unroll
  for (int o = 1; o < 9; ++o) s += p[o * 512];
  sim[idx] = s * (1.f / 9.f);  // sim[(a*8+b)*4096 + i*64 + j]
}

// ---------- kernel 3: conv1 (1->32, 3x3 same) + ReLU + maxpool2 -------------
__global__ __launch_bounds__(256) void k_conv1pool(const float* __restrict__ sim,
                                                   const float* __restrict__ w1,
                                                   const float* __restrict__ b1,
                                                   float* __restrict__ out) {
  __shared__ float tin[4096];  // 64x64 input
  const int pair = blockIdx.x, ocg = blockIdx.y, tid = threadIdx.x;
  const float4* src = (const float4*)(sim + (size_t)pair * 4096);
  for (int i = tid; i < 1024; i += 256) ((float4*)tin)[i] = src[i];
  __syncthreads();
  for (int oc8 = 0; oc8 < 8; ++oc8) {
    int oc = ocg * 8 + oc8;
    float wv[9];
#pragma unroll
    for (int q = 0; q < 9; ++q) wv[q] = w1[oc * 9 + q];
    float bias = b1[oc];
    for (int pp = tid; pp < 1024; pp += 256) {
      int py = pp >> 5, px = pp & 31;
      float m = 0.f;  // relu >= 0, so 0 is a valid max identity
#pragma unroll
      for (int dy = 0; dy < 2; ++dy)
#pragma unroll
        for (int dx = 0; dx < 2; ++dx) {
          int yy = py * 2 + dy, xx0 = px * 2 + dx;
          float s = bias;
#pragma unroll
          for (int ky = 0; ky < 3; ++ky) {
            int y = yy + ky - 1;
            if ((unsigned)y < 64u) {
#pragma unroll
              for (int kx = 0; kx < 3; ++kx) {
                int x = xx0 + kx - 1;
                if ((unsigned)x < 64u) s += wv[ky * 3 + kx] * tin[y * 64 + x];
              }
            }
          }
          m = fmaxf(m, fmaxf(s, 0.f));
        }
      out[(((size_t)pair * 32 + oc) * 32 + py) * 32 + px] = m;
    }
  }
}

// ---------- kernel 4: conv2 (32->64, 3x3 same) + ReLU + maxpool2 ------------
__global__ __launch_bounds__(256) void k_conv2pool(const float* __restrict__ in,
                                                   const float* __restrict__ w2,
                                                   const float* __restrict__ b2,
                                                   float* __restrict__ out) {
  __shared__ float tin[8 * 1024];  // 8-ic chunk of 32x32 images, 32 KB
  __shared__ float tw[8 * 72];     // [oc8][ic8*9]
  const int pair = blockIdx.x, ocg = blockIdx.y, tid = threadIdx.x;
  const int py = tid >> 4, px = tid & 15;
  float acc[8][4];
#pragma unroll
  for (int o = 0; o < 8; ++o)
#pragma unroll
    for (int d = 0; d < 4; ++d) acc[o][d] = 0.f;

  for (int icc = 0; icc < 4; ++icc) {
    __syncthreads();
    const float4* src = (const float4*)(in + ((size_t)pair * 32 + icc * 8) * 1024);
    for (int i = tid; i < 2048; i += 256) ((float4*)tin)[i] = src[i];
    for (int i = tid; i < 576; i += 256) {
      int oc = i / 72, r = i % 72;
      tw[i] = w2[(ocg * 8 + oc) * 288 + icc * 72 + r];
    }
    __syncthreads();
#pragma unroll
    for (int ic = 0; ic < 8; ++ic) {
      const float* ch = tin + ic * 1024;
      float win[16];  // 4x4 window covering the 2x2 pre-pool conv outputs
#pragma unroll
      for (int wy = 0; wy < 4; ++wy) {
        int y = 2 * py - 1 + wy;
#pragma unroll
        for (int wx = 0; wx < 4; ++wx) {
          int x = 2 * px - 1 + wx;
          win[wy * 4 + wx] = ((unsigned)y < 32u && (unsigned)x < 32u) ? ch[y * 32 + x] : 0.f;
        }
      }
#pragma unroll
      for (int oc = 0; oc < 8; ++oc) {
        const float* w = tw + oc * 72 + ic * 9;
#pragma unroll
        for (int d = 0; d < 4; ++d) {
          int dy = d >> 1, dx = d & 1;
          float s = acc[oc][d];
#pragma unroll
          for (int ky = 0; ky < 3; ++ky)
#pragma unroll
            for (int kx = 0; kx < 3; ++kx)
              s += w[ky * 3 + kx] * win[(dy + ky) * 4 + (dx + kx)];
          acc[oc][d] = s;
        }
      }
    }
  }
#pragma unroll
  for (int oc = 0; oc < 8; ++oc) {
    float bias = b2[ocg * 8 + oc];
    float m = 0.f;
#pragma unroll
    for (int d = 0; d < 4; ++d) m = fmaxf(m, fmaxf(acc[oc][d] + bias, 0.f));
    out[(((size_t)pair * 64 + ocg * 8 + oc) * 16 + py) * 16 + px] = m;
  }
}

// ---------- kernel 5: conv3 (64->128, 3x3 same) + ReLU ----------------------
// Restructured (R1): oc chunk of 8 (grid.y=16), acc[8], capped ic unroll —
// previous version (acc[16], full ic x oc unroll) hit VGPR=256 + scratch
// spill => 6.7 GB HBM traffic, 2.68 ms. Mirror conv2's known-safe shape.
__global__ __launch_bounds__(256) void k_conv3(const float* __restrict__ in,
                                               const float* __restrict__ w3,
                                               const float* __restrict__ b3,
                                               float* __restrict__ out) {
  __shared__ float tin[16 * 256];  // 16-ic chunk of 16x16 images, 16 KB
  __shared__ float tw[8 * 144];    // [oc8][ic16*9], 4.5 KB
  const int pair = blockIdx.x, ocg = blockIdx.y, tid = threadIdx.x;
  const int y = tid >> 4, x = tid & 15;
  float acc[8];
#pragma unroll
  for (int o = 0; o < 8; ++o) acc[o] = 0.f;
  for (int icc = 0; icc < 4; ++icc) {
    __syncthreads();
    const float4* src = (const float4*)(in + ((size_t)pair * 64 + icc * 16) * 256);
    for (int i = tid; i < 1024; i += 256) ((float4*)tin)[i] = src[i];
    for (int i = tid; i < 1152; i += 256) {
      int oc = i / 144, r = i % 144;
      tw[i] = w3[(ocg * 8 + oc) * 576 + icc * 144 + r];
    }
    __syncthreads();
#pragma unroll 2
    for (int ic = 0; ic < 16; ++ic) {
      const float* ch = tin + ic * 256;
      float win[9];
#pragma unroll
      for (int ky = 0; ky < 3; ++ky) {
        int yy = y + ky - 1;
#pragma unroll
        for (int kx = 0; kx < 3; ++kx) {
          int xw = x + kx - 1;
          win[ky * 3 + kx] = ((unsigned)yy < 16u && (unsigned)xw < 16u) ? ch[yy * 16 + xw] : 0.f;
        }
      }
#pragma unroll
      for (int oc = 0; oc < 8; ++oc) {
        const float* w = tw + oc * 144 + ic * 9;
        float s = acc[oc];
#pragma unroll
        for (int q = 0; q < 9; ++q) s += w[q] * win[q];
        acc[oc] = s;
      }
    }
  }
#pragma unroll
  for (int oc = 0; oc < 8; ++oc)
    out[((size_t)pair * 128 + ocg * 8 + oc) * 256 + tid] =
        fmaxf(acc[oc] + b3[ocg * 8 + oc], 0.f);
}

// ---------- kernel 6: zero the output (loss accumulator) --------------------
__global__ void k_zero(float* __restrict__ out) {
  if (threadIdx.x < 65) out[threadIdx.x] = 0.f;
}

// ---------- kernel 7: conv4 1x1 (128->1) + loss + hardtanh + chamfer --------
__global__ __launch_bounds__(256) void k_conv4(const float* __restrict__ h3,
                                               const float* __restrict__ w4,
                                               const float* __restrict__ b4,
                                               float* __restrict__ out) {
  __shared__ float ws4[128];
  __shared__ float rowmax[16];
  __shared__ float lsum[4];
  const int pair = blockIdx.x, tid = threadIdx.x;
  if (tid < 128) ws4[tid] = w4[tid];
  __syncthreads();
  float h = b4[0];
  const float* p = h3 + (size_t)pair * 128 * 256 + tid;
#pragma unroll 8
  for (int ic = 0; ic < 128; ++ic) h += ws4[ic] * p[ic * 256];
  float loss = fmaxf(-(h + 1.f), 0.f) + fmaxf(h - 1.f, 0.f);
  float sc = fminf(fmaxf(h, -1.f), 1.f) * 0.5f + 0.5f;
  // max over j (x) within each row of 16 lanes
#pragma unroll
  for (int off = 8; off >= 1; off >>= 1) sc = fmaxf(sc, __shfl_xor(sc, off, 16));
  // loss: full-wave sum
#pragma unroll
  for (int off = 32; off >= 1; off >>= 1) loss += __shfl_xor(loss, off, 64);
  if ((tid & 15) == 0) rowmax[tid >> 4] = sc;
  if ((tid & 63) == 0) lsum[tid >> 6] = loss;
  __syncthreads();
  if (tid == 0) {
    float mean = 0.f;
#pragma unroll
    for (int i = 0; i < 16; ++i) mean += rowmax[i];
    out[pair] = mean * (1.f / 16.f);
    atomicAdd(out + 64, lsum[0] + lsum[1] + lsum[2] + lsum[3]);
  }
}

extern "C" void kernel_launch(void* const* d_in, const int* in_sizes, int n_in,
                              void* d_out, int out_size, void* d_ws, size_t ws_size,
                              hipStream_t stream) {
  (void)in_sizes; (void)n_in; (void)out_size; (void)ws_size;
  const float* x  = (const float*)d_in[0];
  const float* w1 = (const float*)d_in[1];
  const float* b1 = (const float*)d_in[2];
  const float* w2 = (const float*)d_in[3];
  const float* b2 = (const float*)d_in[4];
  const float* w3 = (const float*)d_in[5];
  const float* b3 = (const float*)d_in[6];
  const float* w4 = (const float*)d_in[7];
  const float* b4 = (const float*)d_in[8];
  float* out = (float*)d_out;

  char* ws = (char*)d_ws;
  u16*   Abf  = (u16*)ws;                          // 4,718,592 B
  float* Smax = (float*)(ws + 4718592);            // 9,437,184 B
  float* sim  = (float*)(ws + 14155776);           // 1,048,576 B
  float* h1   = (float*)(ws + 15204352);           // 8,388,608 B
  float* h2   = (float*)(ws + 23592960);           // 4,194,304 B
  float* h3   = (float*)(ws + 27787264);           // 8,388,608 B  (total ~34.5 MB)

  k_cast<<<1152, 256, 0, stream>>>(x, Abf);
  k_gemm_smax<<<dim3(72, 32), 256, 0, stream>>>(Abf, Smax);
  k_reduce_o<<<1024, 256, 0, stream>>>(Smax, sim);
  k_conv1pool<<<dim3(64, 4), 256, 0, stream>>>(sim, w1, b1, h1);
  k_conv2pool<<<dim3(64, 8), 256, 0, stream>>>(h1, w2, b2, h2);
  k_conv3<<<dim3(64, 16), 256, 0, stream>>>(h2, w3, b3, h3);
  k_zero<<<1, 128, 0, stream>>>(out);
  k_conv4<<<64, 256, 0, stream>>>(h3, w4, b4, out);
}

// Round 3
// 318.833 us; speedup vs baseline: 9.7332x; 1.5223x over previous
//
#include <hip/hip_runtime.h>

typedef unsigned short u16;
typedef unsigned int u32;
typedef __bf16 bf16x8 __attribute__((ext_vector_type(8)));
typedef u16 u16x8 __attribute__((ext_vector_type(8)));
typedef float f32x4 __attribute__((ext_vector_type(4)));

__device__ __forceinline__ u16 f2bf(float f) {
  u32 u = __float_as_uint(f);
  u32 r = (u + 0x7FFFu + ((u >> 16) & 1u)) >> 16;  // RNE
  return (u16)r;
}

// ---------------- kernel 0: cast x fp32 -> bf16 A[4608][512] ----------------
__global__ void k_cast(const float* __restrict__ x, u16* __restrict__ A) {
  int t = blockIdx.x * 256 + threadIdx.x;  // 294912 threads, 8 elems each
  const float4* xp = (const float4*)x + (size_t)t * 2;
  float4 v0 = xp[0], v1 = xp[1];
  u16x8 r;
  r[0] = f2bf(v0.x); r[1] = f2bf(v0.y); r[2] = f2bf(v0.z); r[3] = f2bf(v0.w);
  r[4] = f2bf(v1.x); r[5] = f2bf(v1.y); r[6] = f2bf(v1.z); r[7] = f2bf(v1.w);
  *(u16x8*)(A + (size_t)t * 8) = r;
}

// ------- kernel 1: C = A*A^T with fused max over p (col groups of 9) -------
// Tile: 64 rows x 144 cols (144 = LCM(16,9)); writes Smax[4608][512]
__global__ __launch_bounds__(256) void k_gemm_smax(const u16* __restrict__ A,
                                                   float* __restrict__ Smax) {
  __shared__ float smemf[64 * 148];  // 37888 B; overlaid: staging then C-tile
  u16* As = (u16*)smemf;             // 64 rows x 40 (pad; 80 B stride, 16B-aligned)
  u16* Bs = As + 64 * 40;            // 144 rows x 40
  const int rb = blockIdx.x, cb = blockIdx.y;
  const int rowBase = rb * 64, colBase = cb * 144;
  const int tid = threadIdx.x;
  const int wave = tid >> 6, lane = tid & 63;
  const int lrow = lane & 15, lk = lane >> 4;

  f32x4 acc[9];
#pragma unroll
  for (int t = 0; t < 9; ++t) { f32x4 z = {0.f, 0.f, 0.f, 0.f}; acc[t] = z; }

  for (int k0 = 0; k0 < 512; k0 += 32) {
    __syncthreads();
    {
      int row = tid >> 2, kc = tid & 3;  // 256 chunks exactly for As
      *(float4*)(As + row * 40 + kc * 8) =
          *(const float4*)(A + (size_t)(rowBase + row) * 512 + k0 + kc * 8);
      for (int c = tid; c < 576; c += 256) {
        int r2 = c >> 2, k2 = c & 3;
        *(float4*)(Bs + r2 * 40 + k2 * 8) =
            *(const float4*)(A + (size_t)(colBase + r2) * 512 + k0 + k2 * 8);
      }
    }
    __syncthreads();
    bf16x8 af = *(const bf16x8*)(As + (wave * 16 + lrow) * 40 + lk * 8);
#pragma unroll
    for (int t = 0; t < 9; ++t) {
      bf16x8 bfr = *(const bf16x8*)(Bs + (t * 16 + lrow) * 40 + lk * 8);
      acc[t] = __builtin_amdgcn_mfma_f32_16x16x32_bf16(af, bfr, acc[t], 0, 0, 0);
    }
  }
  __syncthreads();
  // dump accumulators: C/D layout col=lane&15, row=(lane>>4)*4+reg [measured]
#pragma unroll
  for (int t = 0; t < 9; ++t)
#pragma unroll
    for (int r = 0; r < 4; ++r)
      smemf[(wave * 16 + lk * 4 + r) * 148 + t * 16 + lrow] = acc[t][r];
  __syncthreads();
  for (int v = tid; v < 1024; v += 256) {
    int row = v >> 4, j = v & 15;
    const float* p = smemf + row * 148 + j * 9;
    float m = p[0];
#pragma unroll
    for (int q = 1; q < 9; ++q) m = fmaxf(m, p[q]);
    Smax[(size_t)(rowBase + row) * 512 + cb * 16 + j] = m;
  }
}

// ---------- kernel 2: mean over o (row groups of 9) -> sim[64][64][64] ------
__global__ void k_reduce_o(const float* __restrict__ Smax, float* __restrict__ sim) {
  int idx = blockIdx.x * 256 + threadIdx.x;  // 262144
  int j = idx & 63, i = (idx >> 6) & 63, b = (idx >> 12) & 7, a = idx >> 15;
  const float* p = Smax + (size_t)((a * 64 + i) * 9) * 512 + b * 64 + j;
  float s = p[0];
#pragma unroll
  for (int o = 1; o < 9; ++o) s += p[o * 512];
  sim[idx] = s * (1.f / 9.f);  // sim[(a*8+b)*4096 + i*64 + j]
}

// ---------- kernel 3: conv1 (1->32, 3x3 same) + ReLU + maxpool2 -------------
__global__ __launch_bounds__(256) void k_conv1pool(const float* __restrict__ sim,
                                                   const float* __restrict__ w1,
                                                   const float* __restrict__ b1,
                                                   float* __restrict__ out) {
  __shared__ float tin[4096];  // 64x64 input
  const int pair = blockIdx.x, ocg = blockIdx.y, tid = threadIdx.x;
  const float4* src = (const float4*)(sim + (size_t)pair * 4096);
  for (int i = tid; i < 1024; i += 256) ((float4*)tin)[i] = src[i];
  __syncthreads();
  for (int oc8 = 0; oc8 < 8; ++oc8) {
    int oc = ocg * 8 + oc8;
    float wv[9];
#pragma unroll
    for (int q = 0; q < 9; ++q) wv[q] = w1[oc * 9 + q];
    float bias = b1[oc];
    for (int pp = tid; pp < 1024; pp += 256) {
      int py = pp >> 5, px = pp & 31;
      float m = 0.f;  // relu >= 0, so 0 is a valid max identity
#pragma unroll
      for (int dy = 0; dy < 2; ++dy)
#pragma unroll
        for (int dx = 0; dx < 2; ++dx) {
          int yy = py * 2 + dy, xx0 = px * 2 + dx;
          float s = bias;
#pragma unroll
          for (int ky = 0; ky < 3; ++ky) {
            int y = yy + ky - 1;
            if ((unsigned)y < 64u) {
#pragma unroll
              for (int kx = 0; kx < 3; ++kx) {
                int x = xx0 + kx - 1;
                if ((unsigned)x < 64u) s += wv[ky * 3 + kx] * tin[y * 64 + x];
              }
            }
          }
          m = fmaxf(m, fmaxf(s, 0.f));
        }
      out[(((size_t)pair * 32 + oc) * 32 + py) * 32 + px] = m;
    }
  }
}

// ---------- kernel 4: conv2 (32->64, 3x3 same) + ReLU + maxpool2 ------------
// Restructured (R2): oc chunk 8->4 (grid.y=16), acc[4][4], ic unroll capped,
// __launch_bounds__(256,2) caps VGPR at 128 — previous shape hit VGPR=256 +
// scratch spill => 544 MB HBM/dispatch, 215 us.
__global__ __launch_bounds__(256, 2) void k_conv2pool(const float* __restrict__ in,
                                                      const float* __restrict__ w2,
                                                      const float* __restrict__ b2,
                                                      float* __restrict__ out) {
  __shared__ float tin[8 * 1024];  // 8-ic chunk of 32x32 images, 32 KB
  __shared__ float tw[4 * 72];     // [oc4][ic8*9]
  const int pair = blockIdx.x, ocg = blockIdx.y, tid = threadIdx.x;
  const int py = tid >> 4, px = tid & 15;
  float acc[4][4];
#pragma unroll
  for (int o = 0; o < 4; ++o)
#pragma unroll
    for (int d = 0; d < 4; ++d) acc[o][d] = 0.f;

  for (int icc = 0; icc < 4; ++icc) {
    __syncthreads();
    const float4* src = (const float4*)(in + ((size_t)pair * 32 + icc * 8) * 1024);
    for (int i = tid; i < 2048; i += 256) ((float4*)tin)[i] = src[i];
    if (tid < 288) {
      int oc = tid / 72, r = tid % 72;
      tw[tid] = w2[(ocg * 4 + oc) * 288 + icc * 72 + r];
    }
    __syncthreads();
#pragma unroll 2
    for (int ic = 0; ic < 8; ++ic) {
      const float* ch = tin + ic * 1024;
      float win[16];  // 4x4 window covering the 2x2 pre-pool conv outputs
#pragma unroll
      for (int wy = 0; wy < 4; ++wy) {
        int y = 2 * py - 1 + wy;
#pragma unroll
        for (int wx = 0; wx < 4; ++wx) {
          int x = 2 * px - 1 + wx;
          win[wy * 4 + wx] = ((unsigned)y < 32u && (unsigned)x < 32u) ? ch[y * 32 + x] : 0.f;
        }
      }
#pragma unroll
      for (int oc = 0; oc < 4; ++oc) {
        const float* w = tw + oc * 72 + ic * 9;
#pragma unroll
        for (int d = 0; d < 4; ++d) {
          int dy = d >> 1, dx = d & 1;
          float s = acc[oc][d];
#pragma unroll
          for (int ky = 0; ky < 3; ++ky)
#pragma unroll
            for (int kx = 0; kx < 3; ++kx)
              s += w[ky * 3 + kx] * win[(dy + ky) * 4 + (dx + kx)];
          acc[oc][d] = s;
        }
      }
    }
  }
#pragma unroll
  for (int oc = 0; oc < 4; ++oc) {
    float bias = b2[ocg * 4 + oc];
    float m = 0.f;
#pragma unroll
    for (int d = 0; d < 4; ++d) m = fmaxf(m, fmaxf(acc[oc][d] + bias, 0.f));
    out[(((size_t)pair * 64 + ocg * 4 + oc) * 16 + py) * 16 + px] = m;
  }
}

// ---------- kernel 5: conv3 (64->128, 3x3 same) + ReLU ----------------------
// Restructured (R1): oc chunk of 8 (grid.y=16), acc[8], capped ic unroll —
// previous version (acc[16], full ic x oc unroll) hit VGPR=256 + scratch
// spill => 6.7 GB HBM traffic, 2.68 ms.
__global__ __launch_bounds__(256) void k_conv3(const float* __restrict__ in,
                                               const float* __restrict__ w3,
                                               const float* __restrict__ b3,
                                               float* __restrict__ out) {
  __shared__ float tin[16 * 256];  // 16-ic chunk of 16x16 images, 16 KB
  __shared__ float tw[8 * 144];    // [oc8][ic16*9], 4.5 KB
  const int pair = blockIdx.x, ocg = blockIdx.y, tid = threadIdx.x;
  const int y = tid >> 4, x = tid & 15;
  float acc[8];
#pragma unroll
  for (int o = 0; o < 8; ++o) acc[o] = 0.f;
  for (int icc = 0; icc < 4; ++icc) {
    __syncthreads();
    const float4* src = (const float4*)(in + ((size_t)pair * 64 + icc * 16) * 256);
    for (int i = tid; i < 1024; i += 256) ((float4*)tin)[i] = src[i];
    for (int i = tid; i < 1152; i += 256) {
      int oc = i / 144, r = i % 144;
      tw[i] = w3[(ocg * 8 + oc) * 576 + icc * 144 + r];
    }
    __syncthreads();
#pragma unroll 2
    for (int ic = 0; ic < 16; ++ic) {
      const float* ch = tin + ic * 256;
      float win[9];
#pragma unroll
      for (int ky = 0; ky < 3; ++ky) {
        int yy = y + ky - 1;
#pragma unroll
        for (int kx = 0; kx < 3; ++kx) {
          int xw = x + kx - 1;
          win[ky * 3 + kx] = ((unsigned)yy < 16u && (unsigned)xw < 16u) ? ch[yy * 16 + xw] : 0.f;
        }
      }
#pragma unroll
      for (int oc = 0; oc < 8; ++oc) {
        const float* w = tw + oc * 144 + ic * 9;
        float s = acc[oc];
#pragma unroll
        for (int q = 0; q < 9; ++q) s += w[q] * win[q];
        acc[oc] = s;
      }
    }
  }
#pragma unroll
  for (int oc = 0; oc < 8; ++oc)
    out[((size_t)pair * 128 + ocg * 8 + oc) * 256 + tid] =
        fmaxf(acc[oc] + b3[ocg * 8 + oc], 0.f);
}

// ---------- kernel 6: zero the output (loss accumulator) --------------------
__global__ void k_zero(float* __restrict__ out) {
  if (threadIdx.x < 65) out[threadIdx.x] = 0.f;
}

// ---------- kernel 7: conv4 1x1 (128->1) + loss + hardtanh + chamfer --------
__global__ __launch_bounds__(256) void k_conv4(const float* __restrict__ h3,
                                               const float* __restrict__ w4,
                                               const float* __restrict__ b4,
                                               float* __restrict__ out) {
  __shared__ float ws4[128];
  __shared__ float rowmax[16];
  __shared__ float lsum[4];
  const int pair = blockIdx.x, tid = threadIdx.x;
  if (tid < 128) ws4[tid] = w4[tid];
  __syncthreads();
  float h = b4[0];
  const float* p = h3 + (size_t)pair * 128 * 256 + tid;
#pragma unroll 8
  for (int ic = 0; ic < 128; ++ic) h += ws4[ic] * p[ic * 256];
  float loss = fmaxf(-(h + 1.f), 0.f) + fmaxf(h - 1.f, 0.f);
  float sc = fminf(fmaxf(h, -1.f), 1.f) * 0.5f + 0.5f;
  // max over j (x) within each row of 16 lanes
#pragma unroll
  for (int off = 8; off >= 1; off >>= 1) sc = fmaxf(sc, __shfl_xor(sc, off, 16));
  // loss: full-wave sum
#pragma unroll
  for (int off = 32; off >= 1; off >>= 1) loss += __shfl_xor(loss, off, 64);
  if ((tid & 15) == 0) rowmax[tid >> 4] = sc;
  if ((tid & 63) == 0) lsum[tid >> 6] = loss;
  __syncthreads();
  if (tid == 0) {
    float mean = 0.f;
#pragma unroll
    for (int i = 0; i < 16; ++i) mean += rowmax[i];
    out[pair] = mean * (1.f / 16.f);
    atomicAdd(out + 64, lsum[0] + lsum[1] + lsum[2] + lsum[3]);
  }
}

extern "C" void kernel_launch(void* const* d_in, const int* in_sizes, int n_in,
                              void* d_out, int out_size, void* d_ws, size_t ws_size,
                              hipStream_t stream) {
  (void)in_sizes; (void)n_in; (void)out_size; (void)ws_size;
  const float* x  = (const float*)d_in[0];
  const float* w1 = (const float*)d_in[1];
  const float* b1 = (const float*)d_in[2];
  const float* w2 = (const float*)d_in[3];
  const float* b2 = (const float*)d_in[4];
  const float* w3 = (const float*)d_in[5];
  const float* b3 = (const float*)d_in[6];
  const float* w4 = (const float*)d_in[7];
  const float* b4 = (const float*)d_in[8];
  float* out = (float*)d_out;

  char* ws = (char*)d_ws;
  u16*   Abf  = (u16*)ws;                          // 4,718,592 B
  float* Smax = (float*)(ws + 4718592);            // 9,437,184 B
  float* sim  = (float*)(ws + 14155776);           // 1,048,576 B
  float* h1   = (float*)(ws + 15204352);           // 8,388,608 B
  float* h2   = (float*)(ws + 23592960);           // 4,194,304 B
  float* h3   = (float*)(ws + 27787264);           // 8,388,608 B  (total ~34.5 MB)

  k_cast<<<1152, 256, 0, stream>>>(x, Abf);
  k_gemm_smax<<<dim3(72, 32), 256, 0, stream>>>(Abf, Smax);
  k_reduce_o<<<1024, 256, 0, stream>>>(Smax, sim);
  k_conv1pool<<<dim3(64, 4), 256, 0, stream>>>(sim, w1, b1, h1);
  k_conv2pool<<<dim3(64, 16), 256, 0, stream>>>(h1, w2, b2, h2);
  k_conv3<<<dim3(64, 16), 256, 0, stream>>>(h2, w3, b3, h3);
  k_zero<<<1, 128, 0, stream>>>(out);
  k_conv4<<<64, 256, 0, stream>>>(h3, w4, b4, out);
}

// Round 4
// 280.994 us; speedup vs baseline: 11.0439x; 1.1347x over previous
//
#include <hip/hip_runtime.h>

typedef unsigned short u16;
typedef unsigned int u32;
typedef __bf16 bf16x8 __attribute__((ext_vector_type(8)));
typedef u16 u16x8 __attribute__((ext_vector_type(8)));
typedef float f32x4 __attribute__((ext_vector_type(4)));

__device__ __forceinline__ u16 f2bf(float f) {
  u32 u = __float_as_uint(f);
  u32 r = (u + 0x7FFFu + ((u >> 16) & 1u)) >> 16;  // RNE
  return (u16)r;
}

// ---------------- kernel 0: cast x fp32 -> bf16 A[4608][512] ----------------
__global__ void k_cast(const float* __restrict__ x, u16* __restrict__ A) {
  int t = blockIdx.x * 256 + threadIdx.x;  // 294912 threads, 8 elems each
  const float4* xp = (const float4*)x + (size_t)t * 2;
  float4 v0 = xp[0], v1 = xp[1];
  u16x8 r;
  r[0] = f2bf(v0.x); r[1] = f2bf(v0.y); r[2] = f2bf(v0.z); r[3] = f2bf(v0.w);
  r[4] = f2bf(v1.x); r[5] = f2bf(v1.y); r[6] = f2bf(v1.z); r[7] = f2bf(v1.w);
  *(u16x8*)(A + (size_t)t * 8) = r;
}

// ------- kernel 1: C = A*A^T with fused max over p (col groups of 9) -------
// Tile: 64 rows x 144 cols (144 = LCM(16,9)); writes Smax[4608][512]
__global__ __launch_bounds__(256) void k_gemm_smax(const u16* __restrict__ A,
                                                   float* __restrict__ Smax) {
  __shared__ float smemf[64 * 148];  // 37888 B; overlaid: staging then C-tile
  u16* As = (u16*)smemf;             // 64 rows x 40 (pad; 80 B stride, 16B-aligned)
  u16* Bs = As + 64 * 40;            // 144 rows x 40
  const int rb = blockIdx.x, cb = blockIdx.y;
  const int rowBase = rb * 64, colBase = cb * 144;
  const int tid = threadIdx.x;
  const int wave = tid >> 6, lane = tid & 63;
  const int lrow = lane & 15, lk = lane >> 4;

  f32x4 acc[9];
#pragma unroll
  for (int t = 0; t < 9; ++t) { f32x4 z = {0.f, 0.f, 0.f, 0.f}; acc[t] = z; }

  for (int k0 = 0; k0 < 512; k0 += 32) {
    __syncthreads();
    {
      int row = tid >> 2, kc = tid & 3;  // 256 chunks exactly for As
      *(float4*)(As + row * 40 + kc * 8) =
          *(const float4*)(A + (size_t)(rowBase + row) * 512 + k0 + kc * 8);
      for (int c = tid; c < 576; c += 256) {
        int r2 = c >> 2, k2 = c & 3;
        *(float4*)(Bs + r2 * 40 + k2 * 8) =
            *(const float4*)(A + (size_t)(colBase + r2) * 512 + k0 + k2 * 8);
      }
    }
    __syncthreads();
    bf16x8 af = *(const bf16x8*)(As + (wave * 16 + lrow) * 40 + lk * 8);
#pragma unroll
    for (int t = 0; t < 9; ++t) {
      bf16x8 bfr = *(const bf16x8*)(Bs + (t * 16 + lrow) * 40 + lk * 8);
      acc[t] = __builtin_amdgcn_mfma_f32_16x16x32_bf16(af, bfr, acc[t], 0, 0, 0);
    }
  }
  __syncthreads();
  // dump accumulators: C/D layout col=lane&15, row=(lane>>4)*4+reg [measured]
#pragma unroll
  for (int t = 0; t < 9; ++t)
#pragma unroll
    for (int r = 0; r < 4; ++r)
      smemf[(wave * 16 + lk * 4 + r) * 148 + t * 16 + lrow] = acc[t][r];
  __syncthreads();
  for (int v = tid; v < 1024; v += 256) {
    int row = v >> 4, j = v & 15;
    const float* p = smemf + row * 148 + j * 9;
    float m = p[0];
#pragma unroll
    for (int q = 1; q < 9; ++q) m = fmaxf(m, p[q]);
    Smax[(size_t)(rowBase + row) * 512 + cb * 16 + j] = m;
  }
}

// ---------- kernel 2: mean over o (row groups of 9) -> sim[64][64][64] ------
__global__ void k_reduce_o(const float* __restrict__ Smax, float* __restrict__ sim) {
  int idx = blockIdx.x * 256 + threadIdx.x;  // 262144
  int j = idx & 63, i = (idx >> 6) & 63, b = (idx >> 12) & 7, a = idx >> 15;
  const float* p = Smax + (size_t)((a * 64 + i) * 9) * 512 + b * 64 + j;
  float s = p[0];
#pragma unroll
  for (int o = 1; o < 9; ++o) s += p[o * 512];
  sim[idx] = s * (1.f / 9.f);  // sim[(a*8+b)*4096 + i*64 + j]
}

// ---------- kernel 3: conv1 (1->32, 3x3 same) + ReLU + maxpool2 -------------
__global__ __launch_bounds__(256) void k_conv1pool(const float* __restrict__ sim,
                                                   const float* __restrict__ w1,
                                                   const float* __restrict__ b1,
                                                   float* __restrict__ out) {
  __shared__ float tin[4096];  // 64x64 input
  const int pair = blockIdx.x, ocg = blockIdx.y, tid = threadIdx.x;
  const float4* src = (const float4*)(sim + (size_t)pair * 4096);
  for (int i = tid; i < 1024; i += 256) ((float4*)tin)[i] = src[i];
  __syncthreads();
  for (int oc8 = 0; oc8 < 8; ++oc8) {
    int oc = ocg * 8 + oc8;
    float wv[9];
#pragma unroll
    for (int q = 0; q < 9; ++q) wv[q] = w1[oc * 9 + q];
    float bias = b1[oc];
    for (int pp = tid; pp < 1024; pp += 256) {
      int py = pp >> 5, px = pp & 31;
      float m = 0.f;  // relu >= 0, so 0 is a valid max identity
#pragma unroll
      for (int dy = 0; dy < 2; ++dy)
#pragma unroll
        for (int dx = 0; dx < 2; ++dx) {
          int yy = py * 2 + dy, xx0 = px * 2 + dx;
          float s = bias;
#pragma unroll
          for (int ky = 0; ky < 3; ++ky) {
            int y = yy + ky - 1;
            if ((unsigned)y < 64u) {
#pragma unroll
              for (int kx = 0; kx < 3; ++kx) {
                int x = xx0 + kx - 1;
                if ((unsigned)x < 64u) s += wv[ky * 3 + kx] * tin[y * 64 + x];
              }
            }
          }
          m = fmaxf(m, fmaxf(s, 0.f));
        }
      out[(((size_t)pair * 32 + oc) * 32 + py) * 32 + px] = m;
    }
  }
}

// ---------- kernel 4: conv2 (32->64, 3x3 same) + ReLU + maxpool2 ------------
// R2: oc chunk 4, acc[4][4] (VGPR=256 spill fix). R3: weights read directly
// from global with block-uniform indices -> s_load into SGPRs; removes the
// 36 ds_read_b32/ic weight reads that made the LDS pipe the bottleneck.
__global__ __launch_bounds__(256, 2) void k_conv2pool(const float* __restrict__ in,
                                                      const float* __restrict__ w2,
                                                      const float* __restrict__ b2,
                                                      float* __restrict__ out) {
  __shared__ float tin[8 * 1024];  // 8-ic chunk of 32x32 images, 32 KB
  const int pair = blockIdx.x, ocg = blockIdx.y, tid = threadIdx.x;
  const int py = tid >> 4, px = tid & 15;
  float acc[4][4];
#pragma unroll
  for (int o = 0; o < 4; ++o)
#pragma unroll
    for (int d = 0; d < 4; ++d) acc[o][d] = 0.f;

  for (int icc = 0; icc < 4; ++icc) {
    __syncthreads();
    const float4* src = (const float4*)(in + ((size_t)pair * 32 + icc * 8) * 1024);
    for (int i = tid; i < 2048; i += 256) ((float4*)tin)[i] = src[i];
    __syncthreads();
#pragma unroll 2
    for (int ic = 0; ic < 8; ++ic) {
      const float* ch = tin + ic * 1024;
      float win[16];  // 4x4 window covering the 2x2 pre-pool conv outputs
#pragma unroll
      for (int wy = 0; wy < 4; ++wy) {
        int y = 2 * py - 1 + wy;
#pragma unroll
        for (int wx = 0; wx < 4; ++wx) {
          int x = 2 * px - 1 + wx;
          win[wy * 4 + wx] = ((unsigned)y < 32u && (unsigned)x < 32u) ? ch[y * 32 + x] : 0.f;
        }
      }
#pragma unroll
      for (int oc = 0; oc < 4; ++oc) {
        // block-uniform index -> scalar loads (SGPR), no LDS traffic
        const float* w = w2 + ((size_t)(ocg * 4 + oc) * 32 + icc * 8 + ic) * 9;
        float wv[9];
#pragma unroll
        for (int q = 0; q < 9; ++q) wv[q] = w[q];
#pragma unroll
        for (int d = 0; d < 4; ++d) {
          int dy = d >> 1, dx = d & 1;
          float s = acc[oc][d];
#pragma unroll
          for (int ky = 0; ky < 3; ++ky)
#pragma unroll
            for (int kx = 0; kx < 3; ++kx)
              s += wv[ky * 3 + kx] * win[(dy + ky) * 4 + (dx + kx)];
          acc[oc][d] = s;
        }
      }
    }
  }
#pragma unroll
  for (int oc = 0; oc < 4; ++oc) {
    float bias = b2[ocg * 4 + oc];
    float m = 0.f;
#pragma unroll
    for (int d = 0; d < 4; ++d) m = fmaxf(m, fmaxf(acc[oc][d] + bias, 0.f));
    out[(((size_t)pair * 64 + ocg * 4 + oc) * 16 + py) * 16 + px] = m;
  }
}

// ---------- kernel 5: conv3 (64->128, 3x3 same) + ReLU ----------------------
// R1: oc chunk 8 (VGPR=256 spill fix). R3: weights via uniform global reads
// (s_load/SGPR) instead of LDS tw — was 72 weight ds_reads per ic vs 72 FMAs,
// LDS-pipe-bound at VALUBusy=54%, 102 us.
__global__ __launch_bounds__(256) void k_conv3(const float* __restrict__ in,
                                               const float* __restrict__ w3,
                                               const float* __restrict__ b3,
                                               float* __restrict__ out) {
  __shared__ float tin[16 * 256];  // 16-ic chunk of 16x16 images, 16 KB
  const int pair = blockIdx.x, ocg = blockIdx.y, tid = threadIdx.x;
  const int y = tid >> 4, x = tid & 15;
  float acc[8];
#pragma unroll
  for (int o = 0; o < 8; ++o) acc[o] = 0.f;
  for (int icc = 0; icc < 4; ++icc) {
    __syncthreads();
    const float4* src = (const float4*)(in + ((size_t)pair * 64 + icc * 16) * 256);
    for (int i = tid; i < 1024; i += 256) ((float4*)tin)[i] = src[i];
    __syncthreads();
#pragma unroll 2
    for (int ic = 0; ic < 16; ++ic) {
      const float* ch = tin + ic * 256;
      float win[9];
#pragma unroll
      for (int ky = 0; ky < 3; ++ky) {
        int yy = y + ky - 1;
#pragma unroll
        for (int kx = 0; kx < 3; ++kx) {
          int xw = x + kx - 1;
          win[ky * 3 + kx] = ((unsigned)yy < 16u && (unsigned)xw < 16u) ? ch[yy * 16 + xw] : 0.f;
        }
      }
#pragma unroll
      for (int oc = 0; oc < 8; ++oc) {
        // block-uniform index -> scalar loads (SGPR), no LDS traffic
        const float* w = w3 + ((size_t)(ocg * 8 + oc) * 64 + icc * 16 + ic) * 9;
        float s = acc[oc];
#pragma unroll
        for (int q = 0; q < 9; ++q) s += w[q] * win[q];
        acc[oc] = s;
      }
    }
  }
#pragma unroll
  for (int oc = 0; oc < 8; ++oc)
    out[((size_t)pair * 128 + ocg * 8 + oc) * 256 + tid] =
        fmaxf(acc[oc] + b3[ocg * 8 + oc], 0.f);
}

// ---------- kernel 6: zero the output (loss accumulator) --------------------
__global__ void k_zero(float* __restrict__ out) {
  if (threadIdx.x < 65) out[threadIdx.x] = 0.f;
}

// ---------- kernel 7: conv4 1x1 (128->1) + loss + hardtanh + chamfer --------
__global__ __launch_bounds__(256) void k_conv4(const float* __restrict__ h3,
                                               const float* __restrict__ w4,
                                               const float* __restrict__ b4,
                                               float* __restrict__ out) {
  __shared__ float ws4[128];
  __shared__ float rowmax[16];
  __shared__ float lsum[4];
  const int pair = blockIdx.x, tid = threadIdx.x;
  if (tid < 128) ws4[tid] = w4[tid];
  __syncthreads();
  float h = b4[0];
  const float* p = h3 + (size_t)pair * 128 * 256 + tid;
#pragma unroll 8
  for (int ic = 0; ic < 128; ++ic) h += ws4[ic] * p[ic * 256];
  float loss = fmaxf(-(h + 1.f), 0.f) + fmaxf(h - 1.f, 0.f);
  float sc = fminf(fmaxf(h, -1.f), 1.f) * 0.5f + 0.5f;
  // max over j (x) within each row of 16 lanes
#pragma unroll
  for (int off = 8; off >= 1; off >>= 1) sc = fmaxf(sc, __shfl_xor(sc, off, 16));
  // loss: full-wave sum
#pragma unroll
  for (int off = 32; off >= 1; off >>= 1) loss += __shfl_xor(loss, off, 64);
  if ((tid & 15) == 0) rowmax[tid >> 4] = sc;
  if ((tid & 63) == 0) lsum[tid >> 6] = loss;
  __syncthreads();
  if (tid == 0) {
    float mean = 0.f;
#pragma unroll
    for (int i = 0; i < 16; ++i) mean += rowmax[i];
    out[pair] = mean * (1.f / 16.f);
    atomicAdd(out + 64, lsum[0] + lsum[1] + lsum[2] + lsum[3]);
  }
}

extern "C" void kernel_launch(void* const* d_in, const int* in_sizes, int n_in,
                              void* d_out, int out_size, void* d_ws, size_t ws_size,
                              hipStream_t stream) {
  (void)in_sizes; (void)n_in; (void)out_size; (void)ws_size;
  const float* x  = (const float*)d_in[0];
  const float* w1 = (const float*)d_in[1];
  const float* b1 = (const float*)d_in[2];
  const float* w2 = (const float*)d_in[3];
  const float* b2 = (const float*)d_in[4];
  const float* w3 = (const float*)d_in[5];
  const float* b3 = (const float*)d_in[6];
  const float* w4 = (const float*)d_in[7];
  const float* b4 = (const float*)d_in[8];
  float* out = (float*)d_out;

  char* ws = (char*)d_ws;
  u16*   Abf  = (u16*)ws;                          // 4,718,592 B
  float* Smax = (float*)(ws + 4718592);            // 9,437,184 B
  float* sim  = (float*)(ws + 14155776);           // 1,048,576 B
  float* h1   = (float*)(ws + 15204352);           // 8,388,608 B
  float* h2   = (float*)(ws + 23592960);           // 4,194,304 B
  float* h3   = (float*)(ws + 27787264);           // 8,388,608 B  (total ~34.5 MB)

  k_cast<<<1152, 256, 0, stream>>>(x, Abf);
  k_gemm_smax<<<dim3(72, 32), 256, 0, stream>>>(Abf, Smax);
  k_reduce_o<<<1024, 256, 0, stream>>>(Smax, sim);
  k_conv1pool<<<dim3(64, 4), 256, 0, stream>>>(sim, w1, b1, h1);
  k_conv2pool<<<dim3(64, 16), 256, 0, stream>>>(h1, w2, b2, h2);
  k_conv3<<<dim3(64, 16), 256, 0, stream>>>(h2, w3, b3, h3);
  k_zero<<<1, 128, 0, stream>>>(out);
  k_conv4<<<64, 256, 0, stream>>>(h3, w4, b4, out);
}

// Round 5
// 269.623 us; speedup vs baseline: 11.5097x; 1.0422x over previous
//
#include <hip/hip_runtime.h>

typedef unsigned short u16;
typedef unsigned int u32;
typedef __bf16 bf16x8 __attribute__((ext_vector_type(8)));
typedef u16 u16x8 __attribute__((ext_vector_type(8)));
typedef float f32x4 __attribute__((ext_vector_type(4)));

__device__ __forceinline__ u16 f2bf(float f) {
  u32 u = __float_as_uint(f);
  u32 r = (u + 0x7FFFu + ((u >> 16) & 1u)) >> 16;  // RNE
  return (u16)r;
}

// async global->LDS, 16B per lane: LDS dest = wave-uniform base + lane*16
__device__ __forceinline__ void gload16(const void* g, void* l) {
  typedef __attribute__((address_space(1))) const void gvoid;
  typedef __attribute__((address_space(3))) void lvoid;
  __builtin_amdgcn_global_load_lds((gvoid*)g, (lvoid*)l, 16, 0, 0);
}

// ---------------- kernel 0: cast x fp32 -> bf16 A[4608][512] ----------------
__global__ void k_cast(const float* __restrict__ x, u16* __restrict__ A) {
  int t = blockIdx.x * 256 + threadIdx.x;  // 294912 threads, 8 elems each
  const float4* xp = (const float4*)x + (size_t)t * 2;
  float4 v0 = xp[0], v1 = xp[1];
  u16x8 r;
  r[0] = f2bf(v0.x); r[1] = f2bf(v0.y); r[2] = f2bf(v0.z); r[3] = f2bf(v0.w);
  r[4] = f2bf(v1.x); r[5] = f2bf(v1.y); r[6] = f2bf(v1.z); r[7] = f2bf(v1.w);
  *(u16x8*)(A + (size_t)t * 8) = r;
}

// ------- kernel 1: C = A*A^T with fused max over p (col groups of 9) -------
// R4 restructure: block tile 128x288 (4 waves, 2x2), wave-tile 64x144
// (4 row-tiles x 9 col-tiles, acc 36 f32x4), BK=64, global_load_lds staging
// with k-chunk XOR-by-(row&7) swizzle (swizzle applied on the GLOBAL fetch
// side so the DMA's forced base+lane*16 LDS layout ends up conflict-free for
// fragment ds_read_b128). Old: 16x144 wave-tile, VGPR-roundtrip staging,
// 1e7 bank-conflict cycles, MfmaUtil 12.7%, 67 us.
__global__ __launch_bounds__(256) void k_gemm_smax(const u16* __restrict__ A,
                                                   float* __restrict__ Smax) {
  __shared__ char smem[53248];       // A 16KB + B 36KB; epilogue reuses as float
  u16* As = (u16*)smem;              // [row 0..127], row stride 64 u16 (128B), 8 chunks of 16B
  u16* Bs = (u16*)(smem + 16384);    // [col 0..287], same layout
  const int rb = blockIdx.x, cb = blockIdx.y;
  const int rowBase = rb * 128, colBase = cb * 288;
  const int tid = threadIdx.x, wave = tid >> 6, lane = tid & 63;
  const int lr = lane >> 3, lc = lane & 7;   // staging lane map: 8 rows x 8 chunks
  const int lrow = lane & 15, lk = lane >> 4;  // mfma fragment lane map
  const int xr = lrow & 7;                     // row-based k-chunk swizzle
  const int wr = (wave & 1) * 64, wc = (wave >> 1) * 144;

  f32x4 acc[4][9];
#pragma unroll
  for (int rt = 0; rt < 4; ++rt)
#pragma unroll
    for (int ct = 0; ct < 9; ++ct) { f32x4 z = {0.f, 0.f, 0.f, 0.f}; acc[rt][ct] = z; }

  for (int k0 = 0; k0 < 512; k0 += 64) {
    __syncthreads();
    // A-tile: 16 KB = 16 issues of 1KB; 4 per wave. Lane (lr,lc) fetches
    // global chunk lc^lr of row r0+lr -> LDS position lc (swizzled store).
#pragma unroll
    for (int ii = 0; ii < 4; ++ii) {
      int r0 = wave * 32 + ii * 8;
      gload16(A + (size_t)(rowBase + r0 + lr) * 512 + k0 + ((lc ^ lr) * 8),
              As + r0 * 64);
    }
    // B-tile (rows of A serving as C-cols): 36 KB = 36 issues; 9 per wave.
#pragma unroll
    for (int jj = 0; jj < 9; ++jj) {
      int c0 = wave * 72 + jj * 8;
      gload16(A + (size_t)(colBase + c0 + lr) * 512 + k0 + ((lc ^ lr) * 8),
              Bs + c0 * 64);
    }
    __syncthreads();  // drains vmcnt before barrier (compiler-inserted)
#pragma unroll
    for (int s = 0; s < 2; ++s) {
      bf16x8 af[4], bf[9];
#pragma unroll
      for (int rt = 0; rt < 4; ++rt)
        af[rt] = *(const bf16x8*)(As + (wr + rt * 16 + lrow) * 64 +
                                  ((u32)(s * 4 + lk) ^ xr) * 8);
#pragma unroll
      for (int ct = 0; ct < 9; ++ct)
        bf[ct] = *(const bf16x8*)(Bs + (wc + ct * 16 + lrow) * 64 +
                                  ((u32)(s * 4 + lk) ^ xr) * 8);
#pragma unroll
      for (int rt = 0; rt < 4; ++rt)
#pragma unroll
        for (int ct = 0; ct < 9; ++ct)
          acc[rt][ct] = __builtin_amdgcn_mfma_f32_16x16x32_bf16(af[rt], bf[ct],
                                                                acc[rt][ct], 0, 0, 0);
    }
  }

  // Epilogue: per row-tile, dump C (layout col=lane&15, row=(lane>>4)*4+reg)
  // to a per-wave 16x148 LDS slab, then max over col-groups of 9.
  float* epi = (float*)smem + wave * 2368;  // 4 waves x 9472 B = 37888 <= 53248
  const int w2 = wave >> 1;
#pragma unroll
  for (int rt = 0; rt < 4; ++rt) {
    __syncthreads();
#pragma unroll
    for (int ct = 0; ct < 9; ++ct)
#pragma unroll
      for (int r = 0; r < 4; ++r)
        epi[(lk * 4 + r) * 148 + ct * 16 + lrow] = acc[rt][ct][r];
    __syncthreads();
#pragma unroll
    for (int q = 0; q < 4; ++q) {
      int o = lane + 64 * q;  // 16 rows x 16 groups
      int row = o >> 4, g = o & 15;
      const float* p = epi + row * 148 + g * 9;
      float m = p[0];
#pragma unroll
      for (int t = 1; t < 9; ++t) m = fmaxf(m, p[t]);
      Smax[(size_t)(rowBase + wr + rt * 16 + row) * 512 + cb * 32 + w2 * 16 + g] = m;
    }
  }
}

// ---------- kernel 2: mean over o (row groups of 9) -> sim[64][64][64] ------
__global__ void k_reduce_o(const float* __restrict__ Smax, float* __restrict__ sim) {
  int idx = blockIdx.x * 256 + threadIdx.x;  // 262144
  int j = idx & 63, i = (idx >> 6) & 63, b = (idx >> 12) & 7, a = idx >> 15;
  const float* p = Smax + (size_t)((a * 64 + i) * 9) * 512 + b * 64 + j;
  float s = p[0];
#pragma unroll
  for (int o = 1; o < 9; ++o) s += p[o * 512];
  sim[idx] = s * (1.f / 9.f);  // sim[(a*8+b)*4096 + i*64 + j]
}

// ---------- kernel 3: conv1 (1->32, 3x3 same) + ReLU + maxpool2 -------------
__global__ __launch_bounds__(256) void k_conv1pool(const float* __restrict__ sim,
                                                   const float* __restrict__ w1,
                                                   const float* __restrict__ b1,
                                                   float* __restrict__ out) {
  __shared__ float tin[4096];  // 64x64 input
  const int pair = blockIdx.x, ocg = blockIdx.y, tid = threadIdx.x;
  const float4* src = (const float4*)(sim + (size_t)pair * 4096);
  for (int i = tid; i < 1024; i += 256) ((float4*)tin)[i] = src[i];
  __syncthreads();
  for (int oc8 = 0; oc8 < 8; ++oc8) {
    int oc = ocg * 8 + oc8;
    float wv[9];
#pragma unroll
    for (int q = 0; q < 9; ++q) wv[q] = w1[oc * 9 + q];
    float bias = b1[oc];
    for (int pp = tid; pp < 1024; pp += 256) {
      int py = pp >> 5, px = pp & 31;
      float m = 0.f;  // relu >= 0, so 0 is a valid max identity
#pragma unroll
      for (int dy = 0; dy < 2; ++dy)
#pragma unroll
        for (int dx = 0; dx < 2; ++dx) {
          int yy = py * 2 + dy, xx0 = px * 2 + dx;
          float s = bias;
#pragma unroll
          for (int ky = 0; ky < 3; ++ky) {
            int y = yy + ky - 1;
            if ((unsigned)y < 64u) {
#pragma unroll
              for (int kx = 0; kx < 3; ++kx) {
                int x = xx0 + kx - 1;
                if ((unsigned)x < 64u) s += wv[ky * 3 + kx] * tin[y * 64 + x];
              }
            }
          }
          m = fmaxf(m, fmaxf(s, 0.f));
        }
      out[(((size_t)pair * 32 + oc) * 32 + py) * 32 + px] = m;
    }
  }
}

// ---------- kernel 4: conv2 (32->64, 3x3 same) + ReLU + maxpool2 ------------
// R2: oc chunk 4, acc[4][4] (VGPR=256 spill fix). R3: scalar (SGPR) weights.
__global__ __launch_bounds__(256, 2) void k_conv2pool(const float* __restrict__ in,
                                                      const float* __restrict__ w2,
                                                      const float* __restrict__ b2,
                                                      float* __restrict__ out) {
  __shared__ float tin[8 * 1024];  // 8-ic chunk of 32x32 images, 32 KB
  const int pair = blockIdx.x, ocg = blockIdx.y, tid = threadIdx.x;
  const int py = tid >> 4, px = tid & 15;
  float acc[4][4];
#pragma unroll
  for (int o = 0; o < 4; ++o)
#pragma unroll
    for (int d = 0; d < 4; ++d) acc[o][d] = 0.f;

  for (int icc = 0; icc < 4; ++icc) {
    __syncthreads();
    const float4* src = (const float4*)(in + ((size_t)pair * 32 + icc * 8) * 1024);
    for (int i = tid; i < 2048; i += 256) ((float4*)tin)[i] = src[i];
    __syncthreads();
#pragma unroll 2
    for (int ic = 0; ic < 8; ++ic) {
      const float* ch = tin + ic * 1024;
      float win[16];  // 4x4 window covering the 2x2 pre-pool conv outputs
#pragma unroll
      for (int wy = 0; wy < 4; ++wy) {
        int y = 2 * py - 1 + wy;
#pragma unroll
        for (int wx = 0; wx < 4; ++wx) {
          int x = 2 * px - 1 + wx;
          win[wy * 4 + wx] = ((unsigned)y < 32u && (unsigned)x < 32u) ? ch[y * 32 + x] : 0.f;
        }
      }
#pragma unroll
      for (int oc = 0; oc < 4; ++oc) {
        const float* w = w2 + ((size_t)(ocg * 4 + oc) * 32 + icc * 8 + ic) * 9;
        float wv[9];
#pragma unroll
        for (int q = 0; q < 9; ++q) wv[q] = w[q];
#pragma unroll
        for (int d = 0; d < 4; ++d) {
          int dy = d >> 1, dx = d & 1;
          float s = acc[oc][d];
#pragma unroll
          for (int ky = 0; ky < 3; ++ky)
#pragma unroll
            for (int kx = 0; kx < 3; ++kx)
              s += wv[ky * 3 + kx] * win[(dy + ky) * 4 + (dx + kx)];
          acc[oc][d] = s;
        }
      }
    }
  }
#pragma unroll
  for (int oc = 0; oc < 4; ++oc) {
    float bias = b2[ocg * 4 + oc];
    float m = 0.f;
#pragma unroll
    for (int d = 0; d < 4; ++d) m = fmaxf(m, fmaxf(acc[oc][d] + bias, 0.f));
    out[(((size_t)pair * 64 + ocg * 4 + oc) * 16 + py) * 16 + px] = m;
  }
}

// ---------- kernel 5: conv3 (64->128, 3x3 same) + ReLU ----------------------
// R1: oc chunk 8 (spill fix). R3: scalar (SGPR) weights, no LDS weight reads.
__global__ __launch_bounds__(256) void k_conv3(const float* __restrict__ in,
                                               const float* __restrict__ w3,
                                               const float* __restrict__ b3,
                                               float* __restrict__ out) {
  __shared__ float tin[16 * 256];  // 16-ic chunk of 16x16 images, 16 KB
  const int pair = blockIdx.x, ocg = blockIdx.y, tid = threadIdx.x;
  const int y = tid >> 4, x = tid & 15;
  float acc[8];
#pragma unroll
  for (int o = 0; o < 8; ++o) acc[o] = 0.f;
  for (int icc = 0; icc < 4; ++icc) {
    __syncthreads();
    const float4* src = (const float4*)(in + ((size_t)pair * 64 + icc * 16) * 256);
    for (int i = tid; i < 1024; i += 256) ((float4*)tin)[i] = src[i];
    __syncthreads();
#pragma unroll 2
    for (int ic = 0; ic < 16; ++ic) {
      const float* ch = tin + ic * 256;
      float win[9];
#pragma unroll
      for (int ky = 0; ky < 3; ++ky) {
        int yy = y + ky - 1;
#pragma unroll
        for (int kx = 0; kx < 3; ++kx) {
          int xw = x + kx - 1;
          win[ky * 3 + kx] = ((unsigned)yy < 16u && (unsigned)xw < 16u) ? ch[yy * 16 + xw] : 0.f;
        }
      }
#pragma unroll
      for (int oc = 0; oc < 8; ++oc) {
        const float* w = w3 + ((size_t)(ocg * 8 + oc) * 64 + icc * 16 + ic) * 9;
        float s = acc[oc];
#pragma unroll
        for (int q = 0; q < 9; ++q) s += w[q] * win[q];
        acc[oc] = s;
      }
    }
  }
#pragma unroll
  for (int oc = 0; oc < 8; ++oc)
    out[((size_t)pair * 128 + ocg * 8 + oc) * 256 + tid] =
        fmaxf(acc[oc] + b3[ocg * 8 + oc], 0.f);
}

// ---------- kernel 6: zero the output (loss accumulator) --------------------
__global__ void k_zero(float* __restrict__ out) {
  if (threadIdx.x < 65) out[threadIdx.x] = 0.f;
}

// ---------- kernel 7: conv4 1x1 (128->1) + loss + hardtanh + chamfer --------
__global__ __launch_bounds__(256) void k_conv4(const float* __restrict__ h3,
                                               const float* __restrict__ w4,
                                               const float* __restrict__ b4,
                                               float* __restrict__ out) {
  __shared__ float ws4[128];
  __shared__ float rowmax[16];
  __shared__ float lsum[4];
  const int pair = blockIdx.x, tid = threadIdx.x;
  if (tid < 128) ws4[tid] = w4[tid];
  __syncthreads();
  float h = b4[0];
  const float* p = h3 + (size_t)pair * 128 * 256 + tid;
#pragma unroll 8
  for (int ic = 0; ic < 128; ++ic) h += ws4[ic] * p[ic * 256];
  float loss = fmaxf(-(h + 1.f), 0.f) + fmaxf(h - 1.f, 0.f);
  float sc = fminf(fmaxf(h, -1.f), 1.f) * 0.5f + 0.5f;
#pragma unroll
  for (int off = 8; off >= 1; off >>= 1) sc = fmaxf(sc, __shfl_xor(sc, off, 16));
#pragma unroll
  for (int off = 32; off >= 1; off >>= 1) loss += __shfl_xor(loss, off, 64);
  if ((tid & 15) == 0) rowmax[tid >> 4] = sc;
  if ((tid & 63) == 0) lsum[tid >> 6] = loss;
  __syncthreads();
  if (tid == 0) {
    float mean = 0.f;
#pragma unroll
    for (int i = 0; i < 16; ++i) mean += rowmax[i];
    out[pair] = mean * (1.f / 16.f);
    atomicAdd(out + 64, lsum[0] + lsum[1] + lsum[2] + lsum[3]);
  }
}

extern "C" void kernel_launch(void* const* d_in, const int* in_sizes, int n_in,
                              void* d_out, int out_size, void* d_ws, size_t ws_size,
                              hipStream_t stream) {
  (void)in_sizes; (void)n_in; (void)out_size; (void)ws_size;
  const float* x  = (const float*)d_in[0];
  const float* w1 = (const float*)d_in[1];
  const float* b1 = (const float*)d_in[2];
  const float* w2 = (const float*)d_in[3];
  const float* b2 = (const float*)d_in[4];
  const float* w3 = (const float*)d_in[5];
  const float* b3 = (const float*)d_in[6];
  const float* w4 = (const float*)d_in[7];
  const float* b4 = (const float*)d_in[8];
  float* out = (float*)d_out;

  char* ws = (char*)d_ws;
  u16*   Abf  = (u16*)ws;                          // 4,718,592 B
  float* Smax = (float*)(ws + 4718592);            // 9,437,184 B
  float* sim  = (float*)(ws + 14155776);           // 1,048,576 B
  float* h1   = (float*)(ws + 15204352);           // 8,388,608 B
  float* h2   = (float*)(ws + 23592960);           // 4,194,304 B
  float* h3   = (float*)(ws + 27787264);           // 8,388,608 B  (total ~34.5 MB)

  k_cast<<<1152, 256, 0, stream>>>(x, Abf);
  k_gemm_smax<<<dim3(36, 16), 256, 0, stream>>>(Abf, Smax);
  k_reduce_o<<<1024, 256, 0, stream>>>(Smax, sim);
  k_conv1pool<<<dim3(64, 4), 256, 0, stream>>>(sim, w1, b1, h1);
  k_conv2pool<<<dim3(64, 16), 256, 0, stream>>>(h1, w2, b2, h2);
  k_conv3<<<dim3(64, 16), 256, 0, stream>>>(h2, w3, b3, h3);
  k_zero<<<1, 128, 0, stream>>>(out);
  k_conv4<<<64, 256, 0, stream>>>(h3, w4, b4, out);
}

// Round 6
// 266.686 us; speedup vs baseline: 11.6364x; 1.0110x over previous
//
#include <hip/hip_runtime.h>

typedef unsigned short u16;
typedef unsigned int u32;
typedef __bf16 bf16x8 __attribute__((ext_vector_type(8)));
typedef u16 u16x8 __attribute__((ext_vector_type(8)));
typedef float f32x4 __attribute__((ext_vector_type(4)));

__device__ __forceinline__ u16 f2bf(float f) {
  u32 u = __float_as_uint(f);
  u32 r = (u + 0x7FFFu + ((u >> 16) & 1u)) >> 16;  // RNE
  return (u16)r;
}

// async global->LDS, 16B per lane: LDS dest = wave-uniform base + lane*16
__device__ __forceinline__ void gload16(const void* g, void* l) {
  typedef __attribute__((address_space(1))) const void gvoid;
  typedef __attribute__((address_space(3))) void lvoid;
  __builtin_amdgcn_global_load_lds((gvoid*)g, (lvoid*)l, 16, 0, 0);
}

// ---------------- kernel 0: cast x fp32 -> bf16 A[4608][512] ----------------
__global__ void k_cast(const float* __restrict__ x, u16* __restrict__ A) {
  int t = blockIdx.x * 256 + threadIdx.x;  // 294912 threads, 8 elems each
  const float4* xp = (const float4*)x + (size_t)t * 2;
  float4 v0 = xp[0], v1 = xp[1];
  u16x8 r;
  r[0] = f2bf(v0.x); r[1] = f2bf(v0.y); r[2] = f2bf(v0.z); r[3] = f2bf(v0.w);
  r[4] = f2bf(v1.x); r[5] = f2bf(v1.y); r[6] = f2bf(v1.z); r[7] = f2bf(v1.w);
  *(u16x8*)(A + (size_t)t * 8) = r;
}

// ------- kernel 1: C = A*A^T with fused max over p (col groups of 9) -------
// R4: block tile 128x288 (4 waves, 2x2), wave-tile 64x144, BK=64,
// global_load_lds staging with k-chunk XOR-by-(row&7) swizzle.
__global__ __launch_bounds__(256) void k_gemm_smax(const u16* __restrict__ A,
                                                   float* __restrict__ Smax) {
  __shared__ char smem[53248];       // A 16KB + B 36KB; epilogue reuses as float
  u16* As = (u16*)smem;              // [row 0..127], row stride 64 u16 (128B)
  u16* Bs = (u16*)(smem + 16384);    // [col 0..287], same layout
  const int rb = blockIdx.x, cb = blockIdx.y;
  const int rowBase = rb * 128, colBase = cb * 288;
  const int tid = threadIdx.x, wave = tid >> 6, lane = tid & 63;
  const int lr = lane >> 3, lc = lane & 7;   // staging lane map: 8 rows x 8 chunks
  const int lrow = lane & 15, lk = lane >> 4;  // mfma fragment lane map
  const int xr = lrow & 7;                     // row-based k-chunk swizzle
  const int wr = (wave & 1) * 64, wc = (wave >> 1) * 144;

  f32x4 acc[4][9];
#pragma unroll
  for (int rt = 0; rt < 4; ++rt)
#pragma unroll
    for (int ct = 0; ct < 9; ++ct) { f32x4 z = {0.f, 0.f, 0.f, 0.f}; acc[rt][ct] = z; }

  for (int k0 = 0; k0 < 512; k0 += 64) {
    __syncthreads();
#pragma unroll
    for (int ii = 0; ii < 4; ++ii) {
      int r0 = wave * 32 + ii * 8;
      gload16(A + (size_t)(rowBase + r0 + lr) * 512 + k0 + ((lc ^ lr) * 8),
              As + r0 * 64);
    }
#pragma unroll
    for (int jj = 0; jj < 9; ++jj) {
      int c0 = wave * 72 + jj * 8;
      gload16(A + (size_t)(colBase + c0 + lr) * 512 + k0 + ((lc ^ lr) * 8),
              Bs + c0 * 64);
    }
    __syncthreads();
#pragma unroll
    for (int s = 0; s < 2; ++s) {
      bf16x8 af[4], bf[9];
#pragma unroll
      for (int rt = 0; rt < 4; ++rt)
        af[rt] = *(const bf16x8*)(As + (wr + rt * 16 + lrow) * 64 +
                                  ((u32)(s * 4 + lk) ^ xr) * 8);
#pragma unroll
      for (int ct = 0; ct < 9; ++ct)
        bf[ct] = *(const bf16x8*)(Bs + (wc + ct * 16 + lrow) * 64 +
                                  ((u32)(s * 4 + lk) ^ xr) * 8);
#pragma unroll
      for (int rt = 0; rt < 4; ++rt)
#pragma unroll
        for (int ct = 0; ct < 9; ++ct)
          acc[rt][ct] = __builtin_amdgcn_mfma_f32_16x16x32_bf16(af[rt], bf[ct],
                                                                acc[rt][ct], 0, 0, 0);
    }
  }

  float* epi = (float*)smem + wave * 2368;
  const int w2 = wave >> 1;
#pragma unroll
  for (int rt = 0; rt < 4; ++rt) {
    __syncthreads();
#pragma unroll
    for (int ct = 0; ct < 9; ++ct)
#pragma unroll
      for (int r = 0; r < 4; ++r)
        epi[(lk * 4 + r) * 148 + ct * 16 + lrow] = acc[rt][ct][r];
    __syncthreads();
#pragma unroll
    for (int q = 0; q < 4; ++q) {
      int o = lane + 64 * q;
      int row = o >> 4, g = o & 15;
      const float* p = epi + row * 148 + g * 9;
      float m = p[0];
#pragma unroll
      for (int t = 1; t < 9; ++t) m = fmaxf(m, p[t]);
      Smax[(size_t)(rowBase + wr + rt * 16 + row) * 512 + cb * 32 + w2 * 16 + g] = m;
    }
  }
}

// ---------- kernel 2: mean over o (row groups of 9) -> sim[64][64][64] ------
__global__ void k_reduce_o(const float* __restrict__ Smax, float* __restrict__ sim) {
  int idx = blockIdx.x * 256 + threadIdx.x;  // 262144
  int j = idx & 63, i = (idx >> 6) & 63, b = (idx >> 12) & 7, a = idx >> 15;
  const float* p = Smax + (size_t)((a * 64 + i) * 9) * 512 + b * 64 + j;
  float s = p[0];
#pragma unroll
  for (int o = 1; o < 9; ++o) s += p[o * 512];
  sim[idx] = s * (1.f / 9.f);
}

// ---------- kernel 3: conv1 (1->32, 3x3 same) + ReLU + maxpool2 -------------
__global__ __launch_bounds__(256) void k_conv1pool(const float* __restrict__ sim,
                                                   const float* __restrict__ w1,
                                                   const float* __restrict__ b1,
                                                   float* __restrict__ out) {
  __shared__ float tin[4096];  // 64x64 input
  const int pair = blockIdx.x, ocg = blockIdx.y, tid = threadIdx.x;
  const float4* src = (const float4*)(sim + (size_t)pair * 4096);
  for (int i = tid; i < 1024; i += 256) ((float4*)tin)[i] = src[i];
  __syncthreads();
  for (int oc8 = 0; oc8 < 8; ++oc8) {
    int oc = ocg * 8 + oc8;
    float wv[9];
#pragma unroll
    for (int q = 0; q < 9; ++q) wv[q] = w1[oc * 9 + q];
    float bias = b1[oc];
    for (int pp = tid; pp < 1024; pp += 256) {
      int py = pp >> 5, px = pp & 31;
      float m = 0.f;
#pragma unroll
      for (int dy = 0; dy < 2; ++dy)
#pragma unroll
        for (int dx = 0; dx < 2; ++dx) {
          int yy = py * 2 + dy, xx0 = px * 2 + dx;
          float s = bias;
#pragma unroll
          for (int ky = 0; ky < 3; ++ky) {
            int y = yy + ky - 1;
            if ((unsigned)y < 64u) {
#pragma unroll
              for (int kx = 0; kx < 3; ++kx) {
                int x = xx0 + kx - 1;
                if ((unsigned)x < 64u) s += wv[ky * 3 + kx] * tin[y * 64 + x];
              }
            }
          }
          m = fmaxf(m, fmaxf(s, 0.f));
        }
      out[(((size_t)pair * 32 + oc) * 32 + py) * 32 + px] = m;
    }
  }
}

// ---------- kernel 4: conv2 (32->64, 3x3 same) + ReLU + maxpool2 ------------
// R2: oc chunk 4, acc[4][4] (VGPR=256 spill fix). R3: scalar (SGPR) weights.
__global__ __launch_bounds__(256, 2) void k_conv2pool(const float* __restrict__ in,
                                                      const float* __restrict__ w2,
                                                      const float* __restrict__ b2,
                                                      float* __restrict__ out) {
  __shared__ float tin[8 * 1024];
  const int pair = blockIdx.x, ocg = blockIdx.y, tid = threadIdx.x;
  const int py = tid >> 4, px = tid & 15;
  float acc[4][4];
#pragma unroll
  for (int o = 0; o < 4; ++o)
#pragma unroll
    for (int d = 0; d < 4; ++d) acc[o][d] = 0.f;

  for (int icc = 0; icc < 4; ++icc) {
    __syncthreads();
    const float4* src = (const float4*)(in + ((size_t)pair * 32 + icc * 8) * 1024);
    for (int i = tid; i < 2048; i += 256) ((float4*)tin)[i] = src[i];
    __syncthreads();
#pragma unroll 2
    for (int ic = 0; ic < 8; ++ic) {
      const float* ch = tin + ic * 1024;
      float win[16];
#pragma unroll
      for (int wy = 0; wy < 4; ++wy) {
        int y = 2 * py - 1 + wy;
#pragma unroll
        for (int wx = 0; wx < 4; ++wx) {
          int x = 2 * px - 1 + wx;
          win[wy * 4 + wx] = ((unsigned)y < 32u && (unsigned)x < 32u) ? ch[y * 32 + x] : 0.f;
        }
      }
#pragma unroll
      for (int oc = 0; oc < 4; ++oc) {
        const float* w = w2 + ((size_t)(ocg * 4 + oc) * 32 + icc * 8 + ic) * 9;
        float wv[9];
#pragma unroll
        for (int q = 0; q < 9; ++q) wv[q] = w[q];
#pragma unroll
        for (int d = 0; d < 4; ++d) {
          int dy = d >> 1, dx = d & 1;
          float s = acc[oc][d];
#pragma unroll
          for (int ky = 0; ky < 3; ++ky)
#pragma unroll
            for (int kx = 0; kx < 3; ++kx)
              s += wv[ky * 3 + kx] * win[(dy + ky) * 4 + (dx + kx)];
          acc[oc][d] = s;
        }
      }
    }
  }
#pragma unroll
  for (int oc = 0; oc < 4; ++oc) {
    float bias = b2[ocg * 4 + oc];
    float m = 0.f;
#pragma unroll
    for (int d = 0; d < 4; ++d) m = fmaxf(m, fmaxf(acc[oc][d] + bias, 0.f));
    out[(((size_t)pair * 64 + ocg * 4 + oc) * 16 + py) * 16 + px] = m;
  }
}

// ---------- kernel 5: conv3 (64->128, 3x3 same) + ReLU ----------------------
// R5 restructure: thread = (row, psub, oc-lane), 2 oc + full 16-px row per
// thread, 2 images per block (grid 32x8). Weights are per-lane VGPR loads
// (vmcnt — no SMEM/DS lgkm mixing, which serialized R3 at VALUBusy=29%),
// software-pipelined one k ahead. Input rows in LDS, stride 20 (16B-aligned,
// 4-way max banking) with zero halo rows; all border taps statically elided.
// Per ic: 12 ds_read_b128 vs 276 FMAs -> VALU-bound by construction.
__global__ __launch_bounds__(256) void k_conv3(const float* __restrict__ in,
                                               const float* __restrict__ w3,
                                               const float* __restrict__ b3,
                                               float* __restrict__ out) {
  __shared__ float tin[2 * 16 * 18 * 20];  // [psub][ic][srow 18][col 20] = 46080 B
  const int pg = blockIdx.x, ocg = blockIdx.y, tid = threadIdx.x;
  const int ocl = tid & 7, psub = (tid >> 3) & 1, row = tid >> 4;
  const int oc0 = ocg * 16 + ocl * 2;
  const int pair = pg * 2 + psub;

  // zero halo rows (srow 0 and 17) once; staging only writes rows 1..16
  {
    int img = tid >> 7, rem = tid & 127;
    int ic = rem >> 3, r = rem & 7;
    int srow = (r >> 2) * 17, c4 = r & 3;
    *(float4*)&tin[img * 5760 + ic * 360 + srow * 20 + c4 * 4] =
        make_float4(0.f, 0.f, 0.f, 0.f);
  }

  float acc0[16], acc1[16];
#pragma unroll
  for (int i = 0; i < 16; ++i) { acc0[i] = 0.f; acc1[i] = 0.f; }

  const float* wbase0 = w3 + (size_t)oc0 * 576;        // 64 ic x 9
  const float* wbase1 = w3 + (size_t)(oc0 + 1) * 576;
  float wv0[9], wv1[9];
#pragma unroll
  for (int q = 0; q < 9; ++q) { wv0[q] = wbase0[q]; wv1[q] = wbase1[q]; }

  for (int kidx = 0; kidx < 64; ++kidx) {
    if ((kidx & 15) == 0) {
      int icc = kidx >> 4;
      __syncthreads();
      for (int f = tid; f < 2048; f += 256) {
        int img = f >> 10, rem = f & 1023;
        int ic = rem >> 6, r2 = rem & 63;
        int rr = r2 >> 2, c4 = r2 & 3;
        *(float4*)&tin[img * 5760 + ic * 360 + (rr + 1) * 20 + c4 * 4] =
            *(const float4*)(in + ((size_t)(pg * 2 + img) * 64 + icc * 16 + ic) * 256 +
                             rr * 16 + c4 * 4);
      }
      __syncthreads();
    }
    // prefetch next k-step's weights (VGPR loads, hidden under FMAs)
    int kn = kidx < 63 ? kidx + 1 : 63;
    float wn0[9], wn1[9];
#pragma unroll
    for (int q = 0; q < 9; ++q) {
      wn0[q] = wbase0[kn * 9 + q];
      wn1[q] = wbase1[kn * 9 + q];
    }
    const float* ch = tin + psub * 5760 + (kidx & 15) * 360;
#pragma unroll
    for (int ky = 0; ky < 3; ++ky) {
      const float4* rp = (const float4*)(ch + (row + ky) * 20);
      float4 q0 = rp[0], q1 = rp[1], q2 = rp[2], q3 = rp[3];
      float r[16] = {q0.x, q0.y, q0.z, q0.w, q1.x, q1.y, q1.z, q1.w,
                     q2.x, q2.y, q2.z, q2.w, q3.x, q3.y, q3.z, q3.w};
#pragma unroll
      for (int kx = 0; kx < 3; ++kx) {
        float wa = wv0[ky * 3 + kx], wb = wv1[ky * 3 + kx];
#pragma unroll
        for (int px = 0; px < 16; ++px) {
          int col = px + kx - 1;
          if (col >= 0 && col < 16) {
            acc0[px] += wa * r[col];
            acc1[px] += wb * r[col];
          }
        }
      }
    }
#pragma unroll
    for (int q = 0; q < 9; ++q) { wv0[q] = wn0[q]; wv1[q] = wn1[q]; }
  }

  float bb0 = b3[oc0], bb1 = b3[oc0 + 1];
#pragma unroll
  for (int i = 0; i < 16; ++i) acc0[i] = fmaxf(acc0[i] + bb0, 0.f);
#pragma unroll
  for (int i = 0; i < 16; ++i) acc1[i] = fmaxf(acc1[i] + bb1, 0.f);
  float* o0 = out + ((size_t)pair * 128 + oc0) * 256 + row * 16;
#pragma unroll
  for (int c4 = 0; c4 < 4; ++c4)
    *(float4*)(o0 + c4 * 4) =
        make_float4(acc0[c4 * 4], acc0[c4 * 4 + 1], acc0[c4 * 4 + 2], acc0[c4 * 4 + 3]);
#pragma unroll
  for (int c4 = 0; c4 < 4; ++c4)
    *(float4*)(o0 + 256 + c4 * 4) =
        make_float4(acc1[c4 * 4], acc1[c4 * 4 + 1], acc1[c4 * 4 + 2], acc1[c4 * 4 + 3]);
}

// ---------- kernel 6: zero the output (loss accumulator) --------------------
__global__ void k_zero(float* __restrict__ out) {
  if (threadIdx.x < 65) out[threadIdx.x] = 0.f;
}

// ---------- kernel 7: conv4 1x1 (128->1) + loss + hardtanh + chamfer --------
__global__ __launch_bounds__(256) void k_conv4(const float* __restrict__ h3,
                                               const float* __restrict__ w4,
                                               const float* __restrict__ b4,
                                               float* __restrict__ out) {
  __shared__ float ws4[128];
  __shared__ float rowmax[16];
  __shared__ float lsum[4];
  const int pair = blockIdx.x, tid = threadIdx.x;
  if (tid < 128) ws4[tid] = w4[tid];
  __syncthreads();
  float h = b4[0];
  const float* p = h3 + (size_t)pair * 128 * 256 + tid;
#pragma unroll 8
  for (int ic = 0; ic < 128; ++ic) h += ws4[ic] * p[ic * 256];
  float loss = fmaxf(-(h + 1.f), 0.f) + fmaxf(h - 1.f, 0.f);
  float sc = fminf(fmaxf(h, -1.f), 1.f) * 0.5f + 0.5f;
#pragma unroll
  for (int off = 8; off >= 1; off >>= 1) sc = fmaxf(sc, __shfl_xor(sc, off, 16));
#pragma unroll
  for (int off = 32; off >= 1; off >>= 1) loss += __shfl_xor(loss, off, 64);
  if ((tid & 15) == 0) rowmax[tid >> 4] = sc;
  if ((tid & 63) == 0) lsum[tid >> 6] = loss;
  __syncthreads();
  if (tid == 0) {
    float mean = 0.f;
#pragma unroll
    for (int i = 0; i < 16; ++i) mean += rowmax[i];
    out[pair] = mean * (1.f / 16.f);
    atomicAdd(out + 64, lsum[0] + lsum[1] + lsum[2] + lsum[3]);
  }
}

extern "C" void kernel_launch(void* const* d_in, const int* in_sizes, int n_in,
                              void* d_out, int out_size, void* d_ws, size_t ws_size,
                              hipStream_t stream) {
  (void)in_sizes; (void)n_in; (void)out_size; (void)ws_size;
  const float* x  = (const float*)d_in[0];
  const float* w1 = (const float*)d_in[1];
  const float* b1 = (const float*)d_in[2];
  const float* w2 = (const float*)d_in[3];
  const float* b2 = (const float*)d_in[4];
  const float* w3 = (const float*)d_in[5];
  const float* b3 = (const float*)d_in[6];
  const float* w4 = (const float*)d_in[7];
  const float* b4 = (const float*)d_in[8];
  float* out = (float*)d_out;

  char* ws = (char*)d_ws;
  u16*   Abf  = (u16*)ws;                          // 4,718,592 B
  float* Smax = (float*)(ws + 4718592);            // 9,437,184 B
  float* sim  = (float*)(ws + 14155776);           // 1,048,576 B
  float* h1   = (float*)(ws + 15204352);           // 8,388,608 B
  float* h2   = (float*)(ws + 23592960);           // 4,194,304 B
  float* h3   = (float*)(ws + 27787264);           // 8,388,608 B  (total ~34.5 MB)

  k_cast<<<1152, 256, 0, stream>>>(x, Abf);
  k_gemm_smax<<<dim3(36, 16), 256, 0, stream>>>(Abf, Smax);
  k_reduce_o<<<1024, 256, 0, stream>>>(Smax, sim);
  k_conv1pool<<<dim3(64, 4), 256, 0, stream>>>(sim, w1, b1, h1);
  k_conv2pool<<<dim3(64, 16), 256, 0, stream>>>(h1, w2, b2, h2);
  k_conv3<<<dim3(32, 8), 256, 0, stream>>>(h2, w3, b3, h3);
  k_zero<<<1, 128, 0, stream>>>(out);
  k_conv4<<<64, 256, 0, stream>>>(h3, w4, b4, out);
}

// Round 7
// 177.479 us; speedup vs baseline: 17.4853x; 1.5026x over previous
//
#include <hip/hip_runtime.h>

typedef unsigned short u16;
typedef unsigned int u32;
typedef __bf16 bf16x8 __attribute__((ext_vector_type(8)));
typedef u16 u16x8 __attribute__((ext_vector_type(8)));
typedef float f32x4 __attribute__((ext_vector_type(4)));

__device__ __forceinline__ u16 f2bf(float f) {
  u32 u = __float_as_uint(f);
  u32 r = (u + 0x7FFFu + ((u >> 16) & 1u)) >> 16;  // RNE
  return (u16)r;
}

// async global->LDS, 16B per lane: LDS dest = wave-uniform base + lane*16
__device__ __forceinline__ void gload16(const void* g, void* l) {
  typedef __attribute__((address_space(1))) const void gvoid;
  typedef __attribute__((address_space(3))) void lvoid;
  __builtin_amdgcn_global_load_lds((gvoid*)g, (lvoid*)l, 16, 0, 0);
}

// ---------------- kernel 0: cast x fp32 -> bf16 A[4608][512] ----------------
__global__ void k_cast(const float* __restrict__ x, u16* __restrict__ A) {
  int t = blockIdx.x * 256 + threadIdx.x;
  const float4* xp = (const float4*)x + (size_t)t * 2;
  float4 v0 = xp[0], v1 = xp[1];
  u16x8 r;
  r[0] = f2bf(v0.x); r[1] = f2bf(v0.y); r[2] = f2bf(v0.z); r[3] = f2bf(v0.w);
  r[4] = f2bf(v1.x); r[5] = f2bf(v1.y); r[6] = f2bf(v1.z); r[7] = f2bf(v1.w);
  *(u16x8*)(A + (size_t)t * 8) = r;
}

// ------- kernel 1: C = A*A^T with fused max over p (col groups of 9) -------
// R4: block tile 128x288 (4 waves, 2x2), wave-tile 64x144, BK=64,
// global_load_lds staging with k-chunk XOR-by-(row&7) swizzle.
__global__ __launch_bounds__(256) void k_gemm_smax(const u16* __restrict__ A,
                                                   float* __restrict__ Smax) {
  __shared__ char smem[53248];
  u16* As = (u16*)smem;
  u16* Bs = (u16*)(smem + 16384);
  const int rb = blockIdx.x, cb = blockIdx.y;
  const int rowBase = rb * 128, colBase = cb * 288;
  const int tid = threadIdx.x, wave = tid >> 6, lane = tid & 63;
  const int lr = lane >> 3, lc = lane & 7;
  const int lrow = lane & 15, lk = lane >> 4;
  const int xr = lrow & 7;
  const int wr = (wave & 1) * 64, wc = (wave >> 1) * 144;

  f32x4 acc[4][9];
#pragma unroll
  for (int rt = 0; rt < 4; ++rt)
#pragma unroll
    for (int ct = 0; ct < 9; ++ct) { f32x4 z = {0.f, 0.f, 0.f, 0.f}; acc[rt][ct] = z; }

  for (int k0 = 0; k0 < 512; k0 += 64) {
    __syncthreads();
#pragma unroll
    for (int ii = 0; ii < 4; ++ii) {
      int r0 = wave * 32 + ii * 8;
      gload16(A + (size_t)(rowBase + r0 + lr) * 512 + k0 + ((lc ^ lr) * 8),
              As + r0 * 64);
    }
#pragma unroll
    for (int jj = 0; jj < 9; ++jj) {
      int c0 = wave * 72 + jj * 8;
      gload16(A + (size_t)(colBase + c0 + lr) * 512 + k0 + ((lc ^ lr) * 8),
              Bs + c0 * 64);
    }
    __syncthreads();
#pragma unroll
    for (int s = 0; s < 2; ++s) {
      bf16x8 af[4], bf[9];
#pragma unroll
      for (int rt = 0; rt < 4; ++rt)
        af[rt] = *(const bf16x8*)(As + (wr + rt * 16 + lrow) * 64 +
                                  ((u32)(s * 4 + lk) ^ xr) * 8);
#pragma unroll
      for (int ct = 0; ct < 9; ++ct)
        bf[ct] = *(const bf16x8*)(Bs + (wc + ct * 16 + lrow) * 64 +
                                  ((u32)(s * 4 + lk) ^ xr) * 8);
#pragma unroll
      for (int rt = 0; rt < 4; ++rt)
#pragma unroll
        for (int ct = 0; ct < 9; ++ct)
          acc[rt][ct] = __builtin_amdgcn_mfma_f32_16x16x32_bf16(af[rt], bf[ct],
                                                                acc[rt][ct], 0, 0, 0);
    }
  }

  float* epi = (float*)smem + wave * 2368;
  const int w2 = wave >> 1;
#pragma unroll
  for (int rt = 0; rt < 4; ++rt) {
    __syncthreads();
#pragma unroll
    for (int ct = 0; ct < 9; ++ct)
#pragma unroll
      for (int r = 0; r < 4; ++r)
        epi[(lk * 4 + r) * 148 + ct * 16 + lrow] = acc[rt][ct][r];
    __syncthreads();
#pragma unroll
    for (int q = 0; q < 4; ++q) {
      int o = lane + 64 * q;
      int row = o >> 4, g = o & 15;
      const float* p = epi + row * 148 + g * 9;
      float m = p[0];
#pragma unroll
      for (int t = 1; t < 9; ++t) m = fmaxf(m, p[t]);
      Smax[(size_t)(rowBase + wr + rt * 16 + row) * 512 + cb * 32 + w2 * 16 + g] = m;
    }
  }
}

// ---------- kernel 2: mean over o (row groups of 9) -> sim[64][64][64] ------
__global__ void k_reduce_o(const float* __restrict__ Smax, float* __restrict__ sim) {
  int idx = blockIdx.x * 256 + threadIdx.x;
  int j = idx & 63, i = (idx >> 6) & 63, b = (idx >> 12) & 7, a = idx >> 15;
  const float* p = Smax + (size_t)((a * 64 + i) * 9) * 512 + b * 64 + j;
  float s = p[0];
#pragma unroll
  for (int o = 1; o < 9; ++o) s += p[o * 512];
  sim[idx] = s * (1.f / 9.f);
}

// ---------- kernel W: repack conv weights to [tap][oc][ic] bf16 -------------
__global__ void k_wpack(const float* __restrict__ w2, const float* __restrict__ w3,
                        u16* __restrict__ p2, u16* __restrict__ p3) {
  int i = blockIdx.x * 256 + threadIdx.x;  // 73728 threads
  if (i < 18432) {
    int t = i >> 11, oc = (i >> 5) & 63, ic = i & 31;
    p2[i] = f2bf(w2[(oc * 32 + ic) * 9 + t]);
  }
  {
    int t = i >> 13, oc = (i >> 6) & 127, ic = i & 63;
    p3[i] = f2bf(w3[(oc * 64 + ic) * 9 + t]);
  }
}

// ---------- kernel 3: conv1 (1->32) + ReLU + maxpool2, channels-last bf16 ---
__global__ __launch_bounds__(256) void k_conv1pool(const float* __restrict__ sim,
                                                   const float* __restrict__ w1,
                                                   const float* __restrict__ b1,
                                                   u16* __restrict__ h1) {
  __shared__ float tin[4096];
  const int pair = blockIdx.x, ocg = blockIdx.y, tid = threadIdx.x;
  const float4* src = (const float4*)(sim + (size_t)pair * 4096);
  for (int i = tid; i < 1024; i += 256) ((float4*)tin)[i] = src[i];
  __syncthreads();
  float wv[8][9], bs[8];
#pragma unroll
  for (int o = 0; o < 8; ++o) {
#pragma unroll
    for (int q = 0; q < 9; ++q) wv[o][q] = w1[(ocg * 8 + o) * 9 + q];
    bs[o] = b1[ocg * 8 + o];
  }
  for (int pp = tid; pp < 1024; pp += 256) {
    int py = pp >> 5, px = pp & 31;
    float m[8];
#pragma unroll
    for (int o = 0; o < 8; ++o) m[o] = 0.f;
#pragma unroll
    for (int dy = 0; dy < 2; ++dy)
#pragma unroll
      for (int dx = 0; dx < 2; ++dx) {
        float s[8];
#pragma unroll
        for (int o = 0; o < 8; ++o) s[o] = bs[o];
        int yy = py * 2 + dy, xx0 = px * 2 + dx;
#pragma unroll
        for (int ky = 0; ky < 3; ++ky) {
          int y = yy + ky - 1;
          if ((unsigned)y < 64u) {
#pragma unroll
            for (int kx = 0; kx < 3; ++kx) {
              int x = xx0 + kx - 1;
              if ((unsigned)x < 64u) {
                float v = tin[y * 64 + x];
#pragma unroll
                for (int o = 0; o < 8; ++o) s[o] += wv[o][ky * 3 + kx] * v;
              }
            }
          }
        }
#pragma unroll
        for (int o = 0; o < 8; ++o) m[o] = fmaxf(m[o], fmaxf(s[o], 0.f));
      }
    u16x8 r;
#pragma unroll
    for (int o = 0; o < 8; ++o) r[o] = f2bf(m[o]);
    *(u16x8*)&h1[(((size_t)pair * 32 + py) * 32 + px) * 32 + ocg * 8] = r;
  }
}

// ---------- kernel 4: conv2 MFMA (32->64) + ReLU + maxpool2 -----------------
// R6: 9 tap-shifted GEMMs, channels-last bf16. Block=(pair,yhalf), 4 waves;
// wave = 8 M-tiles (4 rows x 2 xhalves) x 4 N-tiles; K=32 = one MFMA step.
// A-frags from padded LDS tile (ic stride 40: lanes spread over all banks);
// W-frags contiguous from wpack2[tap][oc][ic] (L2-hot).
__global__ __launch_bounds__(256) void k_conv2pool(const u16* __restrict__ h1,
                                                   const u16* __restrict__ wp2,
                                                   const float* __restrict__ b2,
                                                   u16* __restrict__ h2) {
  __shared__ u16 tile[18 * 34 * 40];  // 48960 B
  const int pair = blockIdx.x, yh = blockIdx.y, tid = threadIdx.x;
  const int wave = tid >> 6, lane = tid & 63, l15 = lane & 15, quad = lane >> 4;
  u16x8 z8 = {0, 0, 0, 0, 0, 0, 0, 0};
  for (int i = tid; i < 3060; i += 256) ((u16x8*)tile)[i] = z8;
  __syncthreads();
  for (int f = tid; f < 1152; f += 256) {
    int i = f >> 6, rem = f & 63, px = rem >> 1, half = rem & 1;
    int gr = yh * 16 - 1 + i;
    if ((unsigned)gr < 32u)
      *(u16x8*)&tile[(i * 34 + 1 + px) * 40 + half * 16] =
          *(const u16x8*)&h1[(((size_t)pair * 32 + gr) * 32 + px) * 32 + half * 16];
  }
  __syncthreads();

  f32x4 acc[8][4];
#pragma unroll
  for (int m = 0; m < 8; ++m)
#pragma unroll
    for (int n = 0; n < 4; ++n) { f32x4 z = {0.f, 0.f, 0.f, 0.f}; acc[m][n] = z; }

  for (int t = 0; t < 9; ++t) {
    int ky = t / 3, kx = t % 3;
    bf16x8 wf[4];
#pragma unroll
    for (int nt = 0; nt < 4; ++nt)
      wf[nt] = *(const bf16x8*)&wp2[((t * 64 + nt * 16 + l15) << 5) + quad * 8];
#pragma unroll
    for (int rr = 0; rr < 4; ++rr)
#pragma unroll
      for (int xh = 0; xh < 2; ++xh) {
        int lr = wave * 4 + rr;
        bf16x8 af = *(const bf16x8*)&tile[((lr + ky) * 34 + xh * 16 + l15 + kx) * 40 +
                                          quad * 8];
#pragma unroll
        for (int nt = 0; nt < 4; ++nt)
          acc[rr * 2 + xh][nt] =
              __builtin_amdgcn_mfma_f32_16x16x32_bf16(af, wf[nt], acc[rr * 2 + xh][nt],
                                                      0, 0, 0);
      }
  }

  float bv[4];
#pragma unroll
  for (int nt = 0; nt < 4; ++nt) bv[nt] = b2[nt * 16 + l15];
#pragma unroll
  for (int rp = 0; rp < 2; ++rp)
#pragma unroll
    for (int xh = 0; xh < 2; ++xh) {
      int py = yh * 8 + wave * 2 + rp;
      int px0 = xh * 8 + quad * 2;
#pragma unroll
      for (int nt = 0; nt < 4; ++nt) {
        f32x4 va = acc[(rp * 2) * 2 + xh][nt], vb = acc[(rp * 2 + 1) * 2 + xh][nt];
        float p0 = fmaxf(fmaxf(fmaxf(va[0], va[1]), fmaxf(vb[0], vb[1])) + bv[nt], 0.f);
        float p1 = fmaxf(fmaxf(fmaxf(va[2], va[3]), fmaxf(vb[2], vb[3])) + bv[nt], 0.f);
        size_t base = (((size_t)pair * 16 + py) * 16 + px0) * 64 + nt * 16 + l15;
        h2[base] = f2bf(p0);
        h2[base + 64] = f2bf(p1);
      }
    }
}

// ---------- kernel 5: conv3 MFMA (64->128) + ReLU ---------------------------
// R6: 9 tap-shifted GEMMs, channels-last. Block=(pair,ochalf), 4 waves;
// wave = 4 M-tiles (rows) x 4 N-tiles; K=64 = 2 MFMA steps per tap.
__global__ __launch_bounds__(256) void k_conv3(const u16* __restrict__ h2,
                                               const u16* __restrict__ wp3,
                                               const float* __restrict__ b3,
                                               float* __restrict__ h3) {
  __shared__ u16 tile[18 * 18 * 72];  // 46656 B
  const int pair = blockIdx.x, oh = blockIdx.y, tid = threadIdx.x;
  const int wave = tid >> 6, lane = tid & 63, l15 = lane & 15, quad = lane >> 4;
  u16x8 z8 = {0, 0, 0, 0, 0, 0, 0, 0};
  for (int i = tid; i < 2916; i += 256) ((u16x8*)tile)[i] = z8;
  __syncthreads();
  for (int f = tid; f < 2048; f += 256) {
    int row = f >> 7, rem = f & 127, px = rem >> 3, seg = rem & 7;
    *(u16x8*)&tile[((row + 1) * 18 + px + 1) * 72 + seg * 8] =
        *(const u16x8*)&h2[(((size_t)pair * 16 + row) * 16 + px) * 64 + seg * 8];
  }
  __syncthreads();

  f32x4 acc[4][4];
#pragma unroll
  for (int m = 0; m < 4; ++m)
#pragma unroll
    for (int n = 0; n < 4; ++n) { f32x4 z = {0.f, 0.f, 0.f, 0.f}; acc[m][n] = z; }

  for (int t = 0; t < 9; ++t) {
    int ky = t / 3, kx = t % 3;
#pragma unroll
    for (int s = 0; s < 2; ++s) {
      bf16x8 wf[4];
#pragma unroll
      for (int nt = 0; nt < 4; ++nt)
        wf[nt] = *(const bf16x8*)&wp3[((t * 128 + oh * 64 + nt * 16 + l15) << 6) +
                                      s * 32 + quad * 8];
#pragma unroll
      for (int yt = 0; yt < 4; ++yt) {
        int y = wave * 4 + yt;
        bf16x8 af = *(const bf16x8*)&tile[((y + ky) * 18 + l15 + kx) * 72 + s * 32 +
                                          quad * 8];
#pragma unroll
        for (int nt = 0; nt < 4; ++nt)
          acc[yt][nt] = __builtin_amdgcn_mfma_f32_16x16x32_bf16(af, wf[nt],
                                                                acc[yt][nt], 0, 0, 0);
      }
    }
  }

  float bv[4];
#pragma unroll
  for (int nt = 0; nt < 4; ++nt) bv[nt] = b3[oh * 64 + nt * 16 + l15];
#pragma unroll
  for (int yt = 0; yt < 4; ++yt)
#pragma unroll
    for (int nt = 0; nt < 4; ++nt)
#pragma unroll
      for (int r = 0; r < 4; ++r) {
        int px = (wave * 4 + yt) * 16 + quad * 4 + r;
        h3[((size_t)pair * 256 + px) * 128 + oh * 64 + nt * 16 + l15] =
            fmaxf(acc[yt][nt][r] + bv[nt], 0.f);
      }
}

// ---------- kernel 6: zero the output (loss accumulator) --------------------
__global__ void k_zero(float* __restrict__ out) {
  if (threadIdx.x < 65) out[threadIdx.x] = 0.f;
}

// ---------- kernel 7: conv4 1x1 (128->1) + loss + hardtanh + chamfer --------
// R6: h3 is channels-last fp32 -> per-thread contiguous float4 reads.
__global__ __launch_bounds__(256) void k_conv4(const float* __restrict__ h3,
                                               const float* __restrict__ w4,
                                               const float* __restrict__ b4,
                                               float* __restrict__ out) {
  __shared__ float ws4[128];
  __shared__ float rowmax[16];
  __shared__ float lsum[4];
  const int pair = blockIdx.x, tid = threadIdx.x;
  if (tid < 128) ws4[tid] = w4[tid];
  __syncthreads();
  float h = b4[0];
  const float4* p = (const float4*)(h3 + ((size_t)pair * 256 + tid) * 128);
#pragma unroll 8
  for (int i = 0; i < 32; ++i) {
    float4 v = p[i];
    h += v.x * ws4[i * 4] + v.y * ws4[i * 4 + 1] + v.z * ws4[i * 4 + 2] +
         v.w * ws4[i * 4 + 3];
  }
  float loss = fmaxf(-(h + 1.f), 0.f) + fmaxf(h - 1.f, 0.f);
  float sc = fminf(fmaxf(h, -1.f), 1.f) * 0.5f + 0.5f;
#pragma unroll
  for (int off = 8; off >= 1; off >>= 1) sc = fmaxf(sc, __shfl_xor(sc, off, 16));
#pragma unroll
  for (int off = 32; off >= 1; off >>= 1) loss += __shfl_xor(loss, off, 64);
  if ((tid & 15) == 0) rowmax[tid >> 4] = sc;
  if ((tid & 63) == 0) lsum[tid >> 6] = loss;
  __syncthreads();
  if (tid == 0) {
    float mean = 0.f;
#pragma unroll
    for (int i = 0; i < 16; ++i) mean += rowmax[i];
    out[pair] = mean * (1.f / 16.f);
    atomicAdd(out + 64, lsum[0] + lsum[1] + lsum[2] + lsum[3]);
  }
}

extern "C" void kernel_launch(void* const* d_in, const int* in_sizes, int n_in,
                              void* d_out, int out_size, void* d_ws, size_t ws_size,
                              hipStream_t stream) {
  (void)in_sizes; (void)n_in; (void)out_size; (void)ws_size;
  const float* x  = (const float*)d_in[0];
  const float* w1 = (const float*)d_in[1];
  const float* b1 = (const float*)d_in[2];
  const float* w2 = (const float*)d_in[3];
  const float* b2 = (const float*)d_in[4];
  const float* w3 = (const float*)d_in[5];
  const float* b3 = (const float*)d_in[6];
  const float* w4 = (const float*)d_in[7];
  const float* b4 = (const float*)d_in[8];
  float* out = (float*)d_out;

  char* ws = (char*)d_ws;
  u16*   Abf  = (u16*)ws;                          // 4,718,592 B
  float* Smax = (float*)(ws + 4718592);            // 9,437,184 B
  float* sim  = (float*)(ws + 14155776);           // 1,048,576 B
  u16*   h1   = (u16*)(ws + 15204352);             // 4,194,304 B (bf16 chan-last)
  u16*   h2   = (u16*)(ws + 19398656);             // 2,097,152 B (bf16 chan-last)
  float* h3   = (float*)(ws + 21495808);           // 8,388,608 B (fp32 chan-last)
  u16*   wp2  = (u16*)(ws + 29884416);             //    36,864 B
  u16*   wp3  = (u16*)(ws + 29921280);             //   147,456 B (end ~30.1 MB)

  k_cast<<<1152, 256, 0, stream>>>(x, Abf);
  k_gemm_smax<<<dim3(36, 16), 256, 0, stream>>>(Abf, Smax);
  k_reduce_o<<<1024, 256, 0, stream>>>(Smax, sim);
  k_wpack<<<288, 256, 0, stream>>>(w2, w3, wp2, wp3);
  k_conv1pool<<<dim3(64, 4), 256, 0, stream>>>(sim, w1, b1, h1);
  k_conv2pool<<<dim3(64, 2), 256, 0, stream>>>(h1, wp2, b2, h2);
  k_conv3<<<dim3(64, 2), 256, 0, stream>>>(h2, wp3, b3, h3);
  k_zero<<<1, 128, 0, stream>>>(out);
  k_conv4<<<64, 256, 0, stream>>>(h3, w4, b4, out);
}